// Round 9
// baseline (283.888 us; speedup 1.0000x reference)
//
#include <hip/hip_runtime.h>
#include <stdint.h>

#define BB 2
#define HH 16
#define LL 2048
#define DD 1024
#define HDD 64
#define NC 512

typedef __bf16 bf16x8 __attribute__((ext_vector_type(8)));
typedef float f32x4 __attribute__((ext_vector_type(4)));
typedef unsigned short u16x8 __attribute__((ext_vector_type(8)));
typedef unsigned short u16x4 __attribute__((ext_vector_type(4)));

__device__ __forceinline__ unsigned short f2bf(float f) {
  union { float f; unsigned u; } v; v.f = f;
  unsigned u = v.u;
  u += 0x7fffu + ((u >> 16) & 1u);
  return (unsigned short)(u >> 16);
}
__device__ __forceinline__ float bf2f(unsigned short h) {
  union { unsigned u; float f; } v; v.u = ((unsigned)h) << 16;
  return v.f;
}

// ---------------- cast kernel (vectorized) + fused c2 norms ----------------
__global__ void cast_all(const float* __restrict__ x, const float* __restrict__ wq,
                         const float* __restrict__ wk, const float* __restrict__ wv,
                         const float* __restrict__ wo, const float* __restrict__ cb,
                         unsigned short* __restrict__ xb, unsigned short* __restrict__ xl,
                         unsigned short* __restrict__ wb, unsigned short* __restrict__ wkl,
                         unsigned short* __restrict__ wob, unsigned short* __restrict__ cbb,
                         unsigned short* __restrict__ cbl, float* __restrict__ c2,
                         float* __restrict__ lsum) {
  if (blockIdx.x >= 4096) {  // c2 blocks (32 x 256 threads)
    int i = (blockIdx.x - 4096) * 256 + threadIdx.x;
    if (i < HH * NC) {
      const float* r = cb + (long)i * HDD;
      double s = 0.0;
      for (int j = 0; j < HDD; j++) s += (double)r[j] * (double)r[j];
      c2[i] = (float)s;
    }
    return;
  }
  long i = (long)blockIdx.x * blockDim.x + threadIdx.x;
  if (i == 0) lsum[0] = 0.f;
  const long NX4 = 1048576, NW4 = 262144, NCB4 = 131072;
  const long TOT4 = NX4 + 4 * NW4 + NCB4;
  for (long q = i; q < TOT4; q += (long)4096 * blockDim.x) {
    if (q < NX4) {
      long t = q * 4;
      float4 v = *(const float4*)(x + t);
      u16x4 hi, lo;
#pragma unroll
      for (int j = 0; j < 4; j++) {
        float f = ((const float*)&v)[j];
        unsigned short h = f2bf(f);
        hi[j] = h; lo[j] = f2bf(f - bf2f(h));
      }
      *(u16x4*)(xb + t) = hi;
      *(u16x4*)(xl + t) = lo;
    } else if (q < NX4 + NW4) {
      long t = (q - NX4) * 4;
      float4 v = *(const float4*)(wq + t);
      u16x4 hi;
#pragma unroll
      for (int j = 0; j < 4; j++) hi[j] = f2bf(((const float*)&v)[j]);
      *(u16x4*)(wb + t) = hi;
    } else if (q < NX4 + 2 * NW4) {
      long t = (q - NX4 - NW4) * 4;
      float4 v = *(const float4*)(wk + t);
      u16x4 hi, lo;
#pragma unroll
      for (int j = 0; j < 4; j++) {
        float f = ((const float*)&v)[j];
        unsigned short h = f2bf(f);
        hi[j] = h; lo[j] = f2bf(f - bf2f(h));
      }
      *(u16x4*)(wb + 1048576 + t) = hi;
      *(u16x4*)(wkl + t) = lo;
    } else if (q < NX4 + 3 * NW4) {
      long t = (q - NX4 - 2 * NW4) * 4;
      float4 v = *(const float4*)(wv + t);
      u16x4 hi;
#pragma unroll
      for (int j = 0; j < 4; j++) hi[j] = f2bf(((const float*)&v)[j]);
      *(u16x4*)(wb + 2097152 + t) = hi;
    } else if (q < NX4 + 4 * NW4) {
      long t = (q - NX4 - 3 * NW4) * 4;
      float4 v = *(const float4*)(wo + t);
      u16x4 hi;
#pragma unroll
      for (int j = 0; j < 4; j++) hi[j] = f2bf(((const float*)&v)[j]);
      *(u16x4*)(wob + t) = hi;
    } else {
      long t = (q - NX4 - 4 * NW4) * 4;
      float4 v = *(const float4*)(cb + t);
      u16x4 hi, lo;
#pragma unroll
      for (int j = 0; j < 4; j++) {
        float f = ((const float*)&v)[j];
        unsigned short h = f2bf(f);
        hi[j] = h; lo[j] = f2bf(f - bf2f(h));
      }
      *(u16x4*)(cbb + t) = hi;
      *(u16x4*)(cbl + t) = lo;
    }
  }
}

// ---------------- HORIZONTAL FUSION: gemm_qv + kvq-64row, BK=32, T14 reg-staged ----------------
// gid%3==2 -> qv block; else kvq block. Staging: global->reg (issued during prior
// round's compute) -> ds_write after barrier. Same LDS slots as global_load_lds
// version -> bit-identical outputs; removes the per-round vmcnt(0) drain stall.
__global__ __launch_bounds__(256) void qv_kvq(
    const unsigned short* __restrict__ xb, const unsigned short* __restrict__ xl,
    const unsigned short* __restrict__ wb, const unsigned short* __restrict__ wkl,
    const float* __restrict__ cb, const float* __restrict__ c2,
    const unsigned short* __restrict__ cbb, const unsigned short* __restrict__ cbl,
    unsigned short* __restrict__ qb, unsigned short* __restrict__ vt,
    unsigned short* __restrict__ khat, float* __restrict__ scodes,
    float* __restrict__ lsum) {
  __shared__ __align__(16) char smem[37888];
  int tid = threadIdx.x;
  int wave = tid >> 6, lane = tid & 63;
  int quad = lane >> 4, col = lane & 15;
  int gid = blockIdx.x;
  int cls = gid % 3;

  if (cls == 2) {
    // ================= QV path (BK=32, T14 reg-staged) =================
    unsigned short* As = (unsigned short*)smem;           // 8192 B
    unsigned short* Bs = (unsigned short*)(smem + 8192);  // 8192 B
    int qid = gid / 3;                 // 0..511
    int bx = qid & 15, by = qid >> 4;
    int m0 = by * 128;
    int n0 = bx * 128 + (bx >= 8 ? 1024 : 0);
    f32x4 acc[4][4] = {};
    int row_in = (wave << 4) + (lane >> 2);
    int seg = lane & 3;
    const unsigned short* gA0 = xb + (long)(m0 + row_in) * DD + seg * 8;
    const unsigned short* gA1 = xb + (long)(m0 + 64 + row_in) * DD + seg * 8;
    const unsigned short* gB0 = wb + (long)(n0 + row_in) * DD + seg * 8;
    const unsigned short* gB1 = wb + (long)(n0 + 64 + row_in) * DD + seg * 8;
    unsigned short* wA0 = As + wave * 512 + lane * 8;
    unsigned short* wA1 = As + 2048 + wave * 512 + lane * 8;
    unsigned short* wB0 = Bs + wave * 512 + lane * 8;
    unsigned short* wB1 = Bs + 2048 + wave * 512 + lane * 8;
    int wm = wave & 1, wn = wave >> 1;
    const unsigned short* pa = As + (wm * 64 + col) * 32 + quad * 8;
    const unsigned short* pb = Bs + (wn * 64 + col) * 32 + quad * 8;
    u16x8 rA0 = *(const u16x8*)(gA0);
    u16x8 rA1 = *(const u16x8*)(gA1);
    u16x8 rB0 = *(const u16x8*)(gB0);
    u16x8 rB1 = *(const u16x8*)(gB1);
    for (int kk = 0; kk < DD; kk += 32) {
      __syncthreads();
      *(u16x8*)wA0 = rA0;
      *(u16x8*)wA1 = rA1;
      *(u16x8*)wB0 = rB0;
      *(u16x8*)wB1 = rB1;
      __syncthreads();
      if (kk + 32 < DD) {   // next tile loads hide under this round's compute
        rA0 = *(const u16x8*)(gA0 + kk + 32);
        rA1 = *(const u16x8*)(gA1 + kk + 32);
        rB0 = *(const u16x8*)(gB0 + kk + 32);
        rB1 = *(const u16x8*)(gB1 + kk + 32);
      }
      bf16x8 af[4], bfr[4];
      for (int t = 0; t < 4; t++) af[t]  = *(const bf16x8*)(pa + t * 512);
      for (int t = 0; t < 4; t++) bfr[t] = *(const bf16x8*)(pb + t * 512);
      for (int mt = 0; mt < 4; mt++)
        for (int nt = 0; nt < 4; nt++)
          acc[mt][nt] = __builtin_amdgcn_mfma_f32_16x16x32_bf16(af[mt], bfr[nt], acc[mt][nt], 0, 0, 0);
    }
    for (int mt = 0; mt < 4; mt++)
      for (int nt = 0; nt < 4; nt++) {
        int mbase = m0 + wm * 64 + mt * 16 + quad * 4;
        int n = n0 + wn * 64 + nt * 16 + col;
        int which = n >> 10, e = n & 1023;
        int h = e >> 6, hd = e & 63;
        for (int r = 0; r < 4; r++) {
          int m = mbase + r;
          int b = m >> 11, l = m & 2047;
          unsigned short val = f2bf(acc[mt][nt][r]);
          long bh = (long)(b * HH + h);
          if (which == 0)      qb[(bh * LL + l) * HDD + hd] = val;
          else                 vt[(bh * HDD + hd) * LL + l] = val;
        }
      }
    return;
  }

  // ================= KVQ path: 64-row m-tile, BK=32, T14 reg-staged =================
  unsigned short* Ah = (unsigned short*)smem;            // 4096 B
  unsigned short* Al = (unsigned short*)(smem + 4096);   // 4096 B
  unsigned short* Bh = (unsigned short*)(smem + 8192);   // 4096 B
  unsigned short* Bl = (unsigned short*)(smem + 12288);  // 4096 B
  float* kfL = (float*)smem;                             // 17408 B = 64*68*4 (overlays staging)
  unsigned short* CbHb = (unsigned short*)(smem + 17408);// 2 bufs x 4608 B
  unsigned short* CbLb = (unsigned short*)(smem + 26624);// 2 bufs x 4608 B
  float* Cs = (float*)(smem + 35840);                    // 2048 B

  int kid = (gid / 3) * 2 + cls;       // 0..1023
  int mtile = kid & 63;                // 0..63
  int h = kid >> 6;                    // 0..15
  int m0 = mtile * 64;
  int n0 = h * 64;
  int bgl = m0 >> 11;
  int l0 = m0 & 2047;
  long bh = (long)(bgl * HH + h);
  const float* c2h = c2 + h * NC;
  Cs[tid] = c2h[tid];
  Cs[tid + 256] = c2h[tid + 256];

  // ---------- Phase 1: GEMM 64x64 (split-bf16 3-pass, BK=32, T14) ----------
  f32x4 acc[2][2] = {};
  int row_in = (wave << 4) + (lane >> 2);   // 0..63
  int seg = lane & 3;
  const unsigned short* gAh = xb + (long)(m0 + row_in) * DD + seg * 8;
  const unsigned short* gAl = xl + (long)(m0 + row_in) * DD + seg * 8;
  const unsigned short* gBh = wb + (long)(1048576 + (long)(n0 + row_in) * DD) + seg * 8;
  const unsigned short* gBl = wkl + (long)(n0 + row_in) * DD + seg * 8;
  unsigned short* wAh = Ah + wave * 512 + lane * 8;
  unsigned short* wAl = Al + wave * 512 + lane * 8;
  unsigned short* wBh = Bh + wave * 512 + lane * 8;
  unsigned short* wBl = Bl + wave * 512 + lane * 8;
  int wm = wave & 1, wn = wave >> 1;
  const unsigned short* pah = Ah + (wm * 32 + col) * 32 + quad * 8;
  const unsigned short* pal = Al + (wm * 32 + col) * 32 + quad * 8;
  const unsigned short* pbh = Bh + (wn * 32 + col) * 32 + quad * 8;
  const unsigned short* pbl = Bl + (wn * 32 + col) * 32 + quad * 8;
  u16x8 rAh = *(const u16x8*)(gAh);
  u16x8 rAl = *(const u16x8*)(gAl);
  u16x8 rBh = *(const u16x8*)(gBh);
  u16x8 rBl = *(const u16x8*)(gBl);
  for (int kk = 0; kk < DD; kk += 32) {
    __syncthreads();
    *(u16x8*)wAh = rAh;
    *(u16x8*)wAl = rAl;
    *(u16x8*)wBh = rBh;
    *(u16x8*)wBl = rBl;
    __syncthreads();
    if (kk + 32 < DD) {
      rAh = *(const u16x8*)(gAh + kk + 32);
      rAl = *(const u16x8*)(gAl + kk + 32);
      rBh = *(const u16x8*)(gBh + kk + 32);
      rBl = *(const u16x8*)(gBl + kk + 32);
    }
    bf16x8 ah[2], al[2], bhf[2], blf[2];
    for (int t = 0; t < 2; t++) ah[t] = *(const bf16x8*)(pah + t * 512);
    for (int t = 0; t < 2; t++) al[t] = *(const bf16x8*)(pal + t * 512);
    for (int t = 0; t < 2; t++) bhf[t] = *(const bf16x8*)(pbh + t * 512);
    for (int t = 0; t < 2; t++) blf[t] = *(const bf16x8*)(pbl + t * 512);
    for (int mt = 0; mt < 2; mt++)
      for (int nt = 0; nt < 2; nt++) {
        acc[mt][nt] = __builtin_amdgcn_mfma_f32_16x16x32_bf16(ah[mt], bhf[nt], acc[mt][nt], 0, 0, 0);
        acc[mt][nt] = __builtin_amdgcn_mfma_f32_16x16x32_bf16(ah[mt], blf[nt], acc[mt][nt], 0, 0, 0);
        acc[mt][nt] = __builtin_amdgcn_mfma_f32_16x16x32_bf16(al[mt], bhf[nt], acc[mt][nt], 0, 0, 0);
      }
  }
  // ---------- Phase 2: acc -> kfL[64][68]; stage codebook tile 0 ----------
  __syncthreads();
  const unsigned short* cbbh = cbb + (long)h * NC * HDD;
  const unsigned short* cblh = cbl + (long)h * NC * HDD;
  int srow = tid >> 3;
  int sseg = (tid & 7) * 8;
  const unsigned short* gH = cbbh + (long)srow * HDD + sseg;
  const unsigned short* gL = cblh + (long)srow * HDD + sseg;
  int ldsOff = srow * 72 + sseg;
  u16x8 ph0 = *(const u16x8*)(gH);
  u16x8 pl0 = *(const u16x8*)(gL);
  for (int mt = 0; mt < 2; mt++)
    for (int nt = 0; nt < 2; nt++) {
      int rw = wm * 32 + mt * 16 + quad * 4;
      int hd = wn * 32 + nt * 16 + col;
      for (int r = 0; r < 4; r++)
        kfL[(rw + r) * 68 + hd] = acc[mt][nt][r];
    }
  *(u16x8*)(CbHb + ldsOff) = ph0;
  *(u16x8*)(CbLb + ldsOff) = pl0;
  __syncthreads();

  // ---------- Phase 3: VQ rounds (16 rows/wave) ----------
  bf16x8 bh0, bh1, bl0, bl1;
  float k2;
  {
    const float* kp = kfL + (wave * 16 + col) * 68 + quad * 8;
    float4 t0 = *(const float4*)(kp);
    float4 t1 = *(const float4*)(kp + 4);
    float4 t2 = *(const float4*)(kp + 32);
    float4 t3 = *(const float4*)(kp + 36);
    float fv[16];
    fv[0]=t0.x; fv[1]=t0.y; fv[2]=t0.z; fv[3]=t0.w;
    fv[4]=t1.x; fv[5]=t1.y; fv[6]=t1.z; fv[7]=t1.w;
    fv[8]=t2.x; fv[9]=t2.y; fv[10]=t2.z; fv[11]=t2.w;
    fv[12]=t3.x; fv[13]=t3.y; fv[14]=t3.z; fv[15]=t3.w;
    k2 = 0.f;
#pragma unroll
    for (int j = 0; j < 16; j++) k2 = fmaf(fv[j], fv[j], k2);
    k2 += __shfl_xor(k2, 16);
    k2 += __shfl_xor(k2, 32);
    u16x8 h0, h1, l0u, l1u;
#pragma unroll
    for (int j = 0; j < 8; j++) {
      unsigned short hi = f2bf(fv[j]);
      h0[j] = hi; l0u[j] = f2bf(fv[j] - bf2f(hi));
      unsigned short hi2 = f2bf(fv[8 + j]);
      h1[j] = hi2; l1u[j] = f2bf(fv[8 + j] - bf2f(hi2));
    }
    bh0 = __builtin_bit_cast(bf16x8, h0);
    bh1 = __builtin_bit_cast(bf16x8, h1);
    bl0 = __builtin_bit_cast(bf16x8, l0u);
    bl1 = __builtin_bit_cast(bf16x8, l1u);
  }
  float b1v = 1e38f, b2v = 1e38f;
  int b1i = 0x7fffffff, b2i = 0x7fffffff;
  for (int t = 0; t < 16; t++) {
    int cur = t & 1;
    u16x8 nh, nl;
    if (t < 15) {
      nh = *(const u16x8*)(gH + (t + 1) * 32 * HDD);
      nl = *(const u16x8*)(gL + (t + 1) * 32 * HDD);
    }
    const unsigned short* CbHc = CbHb + cur * 2304;
    const unsigned short* CbLc = CbLb + cur * 2304;
#pragma unroll
    for (int s = 0; s < 2; s++) {
      const unsigned short* rp = CbHc + (s * 16 + col) * 72 + quad * 8;
      const unsigned short* rq = CbLc + (s * 16 + col) * 72 + quad * 8;
      bf16x8 ah0 = *(const bf16x8*)(rp);
      bf16x8 ah1 = *(const bf16x8*)(rp + 32);
      bf16x8 al0 = *(const bf16x8*)(rq);
      bf16x8 al1 = *(const bf16x8*)(rq + 32);
      f32x4 aP = {}, aQ = {};
      aP = __builtin_amdgcn_mfma_f32_16x16x32_bf16(ah0, bh0, aP, 0, 0, 0);
      aQ = __builtin_amdgcn_mfma_f32_16x16x32_bf16(ah1, bh1, aQ, 0, 0, 0);
      aP = __builtin_amdgcn_mfma_f32_16x16x32_bf16(al0, bh0, aP, 0, 0, 0);
      aQ = __builtin_amdgcn_mfma_f32_16x16x32_bf16(al1, bh1, aQ, 0, 0, 0);
      aP = __builtin_amdgcn_mfma_f32_16x16x32_bf16(ah0, bl0, aP, 0, 0, 0);
      aQ = __builtin_amdgcn_mfma_f32_16x16x32_bf16(ah1, bl1, aQ, 0, 0, 0);
      f32x4 c2v = *(const f32x4*)(Cs + t * 32 + s * 16 + quad * 4);
#pragma unroll
      for (int r = 0; r < 4; r++) {
        float val = c2v[r] - 2.0f * (aP[r] + aQ[r]);
        int idx = t * 32 + s * 16 + quad * 4 + r;
        if (val < b1v) { b2v = b1v; b2i = b1i; b1v = val; b1i = idx; }
        else if (val < b2v) { b2v = val; b2i = idx; }
      }
    }
    if (t < 15) {
      *(u16x8*)(CbHb + (cur ^ 1) * 2304 + ldsOff) = nh;
      *(u16x8*)(CbLb + (cur ^ 1) * 2304 + ldsOff) = nl;
    }
    __syncthreads();
  }
#pragma unroll
  for (int d = 16; d <= 32; d <<= 1) {
    float o1v = __shfl_xor(b1v, d); int o1i = __shfl_xor(b1i, d);
    float o2v = __shfl_xor(b2v, d); int o2i = __shfl_xor(b2i, d);
    if (o1v < b1v || (o1v == b1v && o1i < b1i)) {
      float nv; int ni;
      if (b1v < o2v || (b1v == o2v && b1i < o2i)) { nv = b1v; ni = b1i; }
      else { nv = o2v; ni = o2i; }
      b1v = o1v; b1i = o1i; b2v = nv; b2i = ni;
    } else {
      if (o1v < b2v || (o1v == b2v && o1i < b2i)) { b2v = o1v; b2i = o1i; }
    }
  }
  const float DMARG = 0.015625f;
  bool trig = (b2v - b1v <= DMARG);
  float part;
  int widx = b1i;
  if (__any(trig)) {
    const float* kpr = kfL + (wave * 16 + col) * 68 + quad * 8;
    float4 f0 = *(const float4*)(kpr);
    float4 f1 = *(const float4*)(kpr + 4);
    float4 f2 = *(const float4*)(kpr + 32);
    float4 f3 = *(const float4*)(kpr + 36);
    const float* c1p = cb + ((long)h * NC + b1i) * HDD + quad * 8;
    const float* c2p = cb + ((long)h * NC + b2i) * HDD + quad * 8;
    float4 a0 = *(const float4*)(c1p);
    float4 a1 = *(const float4*)(c1p + 4);
    float4 a2 = *(const float4*)(c1p + 32);
    float4 a3 = *(const float4*)(c1p + 36);
    float4 e0 = *(const float4*)(c2p);
    float4 e1 = *(const float4*)(c2p + 4);
    float4 e2 = *(const float4*)(c2p + 32);
    float4 e3 = *(const float4*)(c2p + 36);
    float s1 = 0.f, s2 = 0.f;
#pragma unroll
    for (int j = 0; j < 4; j++) {
      float d;
      d = ((const float*)&f0)[j] - ((const float*)&a0)[j]; s1 = fmaf(d, d, s1);
      d = ((const float*)&f1)[j] - ((const float*)&a1)[j]; s1 = fmaf(d, d, s1);
      d = ((const float*)&f2)[j] - ((const float*)&a2)[j]; s1 = fmaf(d, d, s1);
      d = ((const float*)&f3)[j] - ((const float*)&a3)[j]; s1 = fmaf(d, d, s1);
      d = ((const float*)&f0)[j] - ((const float*)&e0)[j]; s2 = fmaf(d, d, s2);
      d = ((const float*)&f1)[j] - ((const float*)&e1)[j]; s2 = fmaf(d, d, s2);
      d = ((const float*)&f2)[j] - ((const float*)&e2)[j]; s2 = fmaf(d, d, s2);
      d = ((const float*)&f3)[j] - ((const float*)&e3)[j]; s2 = fmaf(d, d, s2);
    }
    s1 += __shfl_xor(s1, 16); s1 += __shfl_xor(s1, 32);
    s2 += __shfl_xor(s2, 16); s2 += __shfl_xor(s2, 32);
    if (trig) {
      if (s2 < s1 || (s2 == s1 && b2i < b1i)) { widx = b2i; part = s2; }
      else { widx = b1i; part = s1; }
    } else {
      part = k2 + b1v;
    }
  } else {
    part = k2 + b1v;
  }
  if (quad != 0) part = 0.f;
  part += __shfl_xor(part, 1);  part += __shfl_xor(part, 2);
  part += __shfl_xor(part, 4);  part += __shfl_xor(part, 8);
  part += __shfl_xor(part, 16); part += __shfl_xor(part, 32);
  if (lane == 0) atomicAdd(lsum, part);
  if (lane < 16)
    scodes[bh * LL + l0 + wave * 16 + lane] = (float)widx;
  // per-wave khat scatter via shfl (16 rows x 64 shorts)
  {
    int rL = lane >> 2;                 // 0..15
    int p = (lane & 3) * 16;
    int code = __shfl(widx, rL);        // lanes 0..15 hold widx for row=lane
    const unsigned short* src = cbbh + (long)code * HDD + p;
    unsigned short* dst = khat + (bh * LL + l0 + wave * 16 + rL) * HDD + p;
    *(u16x8*)(dst)     = *(const u16x8*)(src);
    *(u16x8*)(dst + 8) = *(const u16x8*)(src + 8);
  }
}

// ---------------- flash attention: paired q-tiles + swapped QK^T (key-major softmax) ----------------
__global__ __launch_bounds__(256) void attn_kernel(
    const unsigned short* __restrict__ qb, const unsigned short* __restrict__ khat,
    const unsigned short* __restrict__ vt, unsigned short* __restrict__ attnb) {
  __shared__ __align__(16) unsigned short Pbuf[4][2][16 * 72];  // 18432 B
  __shared__ __align__(16) unsigned short Kbuf[64 * 72];        // 9216 B
  __shared__ __align__(16) unsigned short Vbuf[64 * 72];        // 9216 B
  int tid = threadIdx.x, wave = tid >> 6, lane = tid & 63;
  int quad = lane >> 4, col = lane & 15;
  int id = blockIdx.y * 16 + blockIdx.x;
  int xcd = id & 7, sidx = id >> 3;
  int bh = xcd * 4 + (sidx >> 4);
  int pi = sidx & 15;
  int b = bh >> 4, h = bh & 15;
  int ta = pi, tb = 31 - pi;
  int qbA = ta * 64 + wave * 16;
  int qbB = tb * 64 + wave * 16;
  const unsigned short* qrA = qb + ((long)bh * LL + qbA + col) * HDD;
  const unsigned short* qrB = qb + ((long)bh * LL + qbB + col) * HDD;
  bf16x8 aqA0 = *(const bf16x8*)(qrA + quad * 8);
  bf16x8 aqA1 = *(const bf16x8*)(qrA + 32 + quad * 8);
  bf16x8 aqB0 = *(const bf16x8*)(qrB + quad * 8);
  bf16x8 aqB1 = *(const bf16x8*)(qrB + 32 + quad * 8);
  float lA = 0.f, lB = 0.f;
  f32x4 oA[4] = {}, oB[4] = {};
  unsigned short* PA = Pbuf[wave][0];
  unsigned short* PB = Pbuf[wave][1];
  const unsigned short* kh = khat + (long)bh * LL * HDD;
  const unsigned short* vh = vt + (long)bh * HDD * LL;
  int srow = tid >> 2, sc = (tid & 3) * 8;
  const unsigned short* gK = kh + (long)srow * HDD + sc;
  const unsigned short* gV = vh + (long)srow * LL + sc;
  unsigned short* lK = Kbuf + srow * 72 + sc;
  unsigned short* lV = Vbuf + srow * 72 + sc;
  const float SCL = 0.18033688011112042f;  // log2(e) / 8
  u16x8 rk0 = *(const u16x8*)(gK);
  u16x8 rk1 = *(const u16x8*)(gK + 32);
  u16x8 rv0 = *(const u16x8*)(gV);
  u16x8 rv1 = *(const u16x8*)(gV + 32);
  for (int kt = 0; kt <= tb; kt++) {
    int kbase = kt * 64;
    bool actA = (kt <= ta);
    __syncthreads();
    *(u16x8*)lK        = rk0;
    *(u16x8*)(lK + 32) = rk1;
    *(u16x8*)lV        = rv0;
    *(u16x8*)(lV + 32) = rv1;
    __syncthreads();
    if (kt < tb) {
      const unsigned short* nK = gK + (long)(kt + 1) * 64 * HDD;
      const unsigned short* nV = gV + (kt + 1) * 64;
      rk0 = *(const u16x8*)(nK);
      rk1 = *(const u16x8*)(nK + 32);
      rv0 = *(const u16x8*)(nV);
      rv1 = *(const u16x8*)(nV + 32);
    }
    f32x4 zA[4], zB[4];
    for (int nt = 0; nt < 4; nt++) {
      const unsigned short* krow = Kbuf + (nt * 16 + col) * 72;
      bf16x8 k0 = *(const bf16x8*)(krow + quad * 8);
      bf16x8 k1 = *(const bf16x8*)(krow + 32 + quad * 8);
      f32x4 z = {};
      z = __builtin_amdgcn_mfma_f32_16x16x32_bf16(k0, aqB0, z, 0, 0, 0);
      z = __builtin_amdgcn_mfma_f32_16x16x32_bf16(k1, aqB1, z, 0, 0, 0);
      zB[nt] = z;
      if (actA) {
        f32x4 y = {};
        y = __builtin_amdgcn_mfma_f32_16x16x32_bf16(k0, aqA0, y, 0, 0, 0);
        y = __builtin_amdgcn_mfma_f32_16x16x32_bf16(k1, aqA1, y, 0, 0, 0);
        zA[nt] = y;
      }
    }
    for (int nt = 0; nt < 4; nt++) {
      u16x4 pk;
      for (int r = 0; r < 4; r++) {
        float sc2 = zB[nt][r] * SCL;
        int key = kbase + nt * 16 + quad * 4 + r;
        if (kt == tb && key > qbB + col) sc2 = -1e30f;
        float p = exp2f(sc2);
        lB += p;
        pk[r] = __builtin_bit_cast(unsigned short, (__bf16)p);
      }
      *(u16x4*)(PB + col * 72 + nt * 16 + quad * 4) = pk;
    }
    if (actA) {
      for (int nt = 0; nt < 4; nt++) {
        u16x4 pk;
        for (int r = 0; r < 4; r++) {
          float sc2 = zA[nt][r] * SCL;
          int key = kbase + nt * 16 + quad * 4 + r;
          if (kt == ta && key > qbA + col) sc2 = -1e30f;
          float p = exp2f(sc2);
          lA += p;
          pk[r] = __builtin_bit_cast(unsigned short, (__bf16)p);
        }
        *(u16x4*)(PA + col * 72 + nt * 16 + quad * 4) = pk;
      }
    }
    bf16x8 apB0 = *(const bf16x8*)(PB + col * 72 + quad * 8);
    bf16x8 apB1 = *(const bf16x8*)(PB + col * 72 + 32 + quad * 8);
    bf16x8 apA0, apA1;
    if (actA) {
      apA0 = *(const bf16x8*)(PA + col * 72 + quad * 8);
      apA1 = *(const bf16x8*)(PA + col * 72 + 32 + quad * 8);
    }
    for (int nt = 0; nt < 4; nt++) {
      const unsigned short* vrow = Vbuf + (nt * 16 + col) * 72;
      bf16x8 v0 = *(const bf16x8*)(vrow + quad * 8);
      bf16x8 v1 = *(const bf16x8*)(vrow + 32 + quad * 8);
      oB[nt] = __builtin_amdgcn_mfma_f32_16x16x32_bf16(apB0, v0, oB[nt], 0, 0, 0);
      oB[nt] = __builtin_amdgcn_mfma_f32_16x16x32_bf16(apB1, v1, oB[nt], 0, 0, 0);
      if (actA) {
        oA[nt] = __builtin_amdgcn_mfma_f32_16x16x32_bf16(apA0, v0, oA[nt], 0, 0, 0);
        oA[nt] = __builtin_amdgcn_mfma_f32_16x16x32_bf16(apA1, v1, oA[nt], 0, 0, 0);
      }
    }
  }
  lA += __shfl_xor(lA, 16); lA += __shfl_xor(lA, 32);
  lB += __shfl_xor(lB, 16); lB += __shfl_xor(lB, 32);
  float invAc = 1.0f / lA;
  float invBc = 1.0f / lB;
  for (int r = 0; r < 4; r++) {
    float invA = __shfl(invAc, quad * 4 + r);
    float invB = __shfl(invBc, quad * 4 + r);
    int rowA = qbA + quad * 4 + r;
    int rowB = qbB + quad * 4 + r;
    for (int nt = 0; nt < 4; nt++) {
      int hd = nt * 16 + col;
      attnb[((long)b * LL + rowA) * DD + h * HDD + hd] = f2bf(oA[nt][r] * invA);
      attnb[((long)b * LL + rowB) * DD + h * HDD + hd] = f2bf(oB[nt][r] * invB);
    }
  }
}

// ---------------- GEMM2: out = attn * Wo^T, 128x64 tiles, BK=32, T14 reg-staged ----------------
__global__ __launch_bounds__(256) void gemm_out(
    const unsigned short* __restrict__ attnb, const unsigned short* __restrict__ wob,
    float* __restrict__ out) {
  __shared__ __align__(16) unsigned short As[128 * 32];
  __shared__ __align__(16) unsigned short Bs[64 * 32];
  int tid = threadIdx.x;
  int wave = tid >> 6, lane = tid & 63;
  int quad = lane >> 4, col = lane & 15;
  int m0 = blockIdx.y * 128;
  int n0 = blockIdx.x * 64;
  f32x4 acc[4][2] = {};
  int row_in = (wave << 4) + (lane >> 2);
  int seg = lane & 3;
  const unsigned short* gA0 = attnb + (long)(m0 + row_in) * DD + seg * 8;
  const unsigned short* gA1 = attnb + (long)(m0 + 64 + row_in) * DD + seg * 8;
  const unsigned short* gB0 = wob + (long)(n0 + row_in) * DD + seg * 8;
  unsigned short* wA0 = As + wave * 512 + lane * 8;
  unsigned short* wA1 = As + 2048 + wave * 512 + lane * 8;
  unsigned short* wB0 = Bs + wave * 512 + lane * 8;
  int wm = wave & 1, wn = wave >> 1;
  const unsigned short* pa = As + (wm * 64 + col) * 32 + quad * 8;
  const unsigned short* pb = Bs + (wn * 32 + col) * 32 + quad * 8;
  u16x8 rA0 = *(const u16x8*)(gA0);
  u16x8 rA1 = *(const u16x8*)(gA1);
  u16x8 rB0 = *(const u16x8*)(gB0);
  for (int kk = 0; kk < DD; kk += 32) {
    __syncthreads();
    *(u16x8*)wA0 = rA0;
    *(u16x8*)wA1 = rA1;
    *(u16x8*)wB0 = rB0;
    __syncthreads();
    if (kk + 32 < DD) {
      rA0 = *(const u16x8*)(gA0 + kk + 32);
      rA1 = *(const u16x8*)(gA1 + kk + 32);
      rB0 = *(const u16x8*)(gB0 + kk + 32);
    }
    bf16x8 af[4], bfr[2];
    for (int t = 0; t < 4; t++) af[t]  = *(const bf16x8*)(pa + t * 512);
    for (int t = 0; t < 2; t++) bfr[t] = *(const bf16x8*)(pb + t * 512);
    for (int mt = 0; mt < 4; mt++)
      for (int nt = 0; nt < 2; nt++)
        acc[mt][nt] = __builtin_amdgcn_mfma_f32_16x16x32_bf16(af[mt], bfr[nt], acc[mt][nt], 0, 0, 0);
  }
  for (int mt = 0; mt < 4; mt++)
    for (int nt = 0; nt < 2; nt++) {
      int mbase = m0 + wm * 64 + mt * 16 + quad * 4;
      int n = n0 + wn * 32 + nt * 16 + col;
      for (int r = 0; r < 4; r++)
        out[(long)(mbase + r) * DD + n] = acc[mt][nt][r];
    }
}

// ---------------- finalize scalars ----------------
__global__ void finalize(const float* __restrict__ lsum, float* __restrict__ out) {
  if (threadIdx.x == 0) {
    float v = lsum[0] / (float)(BB * HH * LL);
    out[4194304] = v;
    out[4194305] = v;
  }
}

extern "C" void kernel_launch(void* const* d_in, const int* in_sizes, int n_in,
                              void* d_out, int out_size, void* d_ws, size_t ws_size,
                              hipStream_t stream) {
  const float* x  = (const float*)d_in[0];
  const float* wq = (const float*)d_in[1];
  const float* wk = (const float*)d_in[2];
  const float* wv = (const float*)d_in[3];
  const float* wo = (const float*)d_in[4];
  const float* cb = (const float*)d_in[5];
  float* out = (float*)d_out;

  char* ws = (char*)d_ws;
  size_t off = 0;
  auto alloc = [&](size_t bytes) {
    void* p = ws + off;
    off = (off + bytes + 255) & ~(size_t)255;
    return p;
  };
  unsigned short* xb    = (unsigned short*)alloc(4194304 * 2);
  unsigned short* xl    = (unsigned short*)alloc(4194304 * 2);
  unsigned short* wb    = (unsigned short*)alloc(3145728 * 2);
  unsigned short* wkl   = (unsigned short*)alloc(1048576 * 2);
  unsigned short* wob   = (unsigned short*)alloc(1048576 * 2);
  unsigned short* cbb   = (unsigned short*)alloc(524288 * 2);
  unsigned short* cbl   = (unsigned short*)alloc(524288 * 2);
  unsigned short* qb    = (unsigned short*)alloc(4194304 * 2);
  unsigned short* vt    = (unsigned short*)alloc(4194304 * 2);
  unsigned short* khat  = (unsigned short*)alloc(4194304 * 2);
  unsigned short* attnb = (unsigned short*)alloc(4194304 * 2);
  float* c2   = (float*)alloc(8192 * 4);
  float* lsum = (float*)alloc(256);

  cast_all<<<dim3(4128), dim3(256), 0, stream>>>(x, wq, wk, wv, wo, cb, xb, xl, wb, wkl, wob, cbb, cbl, c2, lsum);
  qv_kvq<<<dim3(1536), dim3(256), 0, stream>>>(xb, xl, wb, wkl, cb, c2, cbb, cbl, qb, vt, khat, out + 4194306, lsum);
  attn_kernel<<<dim3(16, 32), dim3(256), 0, stream>>>(qb, khat, vt, attnb);
  gemm_out<<<dim3(16, 32), dim3(256), 0, stream>>>(attnb, wob, out);
  finalize<<<dim3(1), dim3(64), 0, stream>>>(lsum, out);
}

// Round 10
// 274.682 us; speedup vs baseline: 1.0335x; 1.0335x over previous
//
#include <hip/hip_runtime.h>
#include <stdint.h>

#define BB 2
#define HH 16
#define LL 2048
#define DD 1024
#define HDD 64
#define NC 512

typedef __bf16 bf16x8 __attribute__((ext_vector_type(8)));
typedef float f32x4 __attribute__((ext_vector_type(4)));
typedef unsigned short u16x8 __attribute__((ext_vector_type(8)));
typedef unsigned short u16x4 __attribute__((ext_vector_type(4)));

__device__ __forceinline__ unsigned short f2bf(float f) {
  union { float f; unsigned u; } v; v.f = f;
  unsigned u = v.u;
  u += 0x7fffu + ((u >> 16) & 1u);
  return (unsigned short)(u >> 16);
}
__device__ __forceinline__ float bf2f(unsigned short h) {
  union { unsigned u; float f; } v; v.u = ((unsigned)h) << 16;
  return v.f;
}

// async global->LDS, 16B per lane; lds ptr must be wave-uniform base (HW adds lane*16)
__device__ __forceinline__ void load_lds16(const unsigned short* g, unsigned short* l) {
  __builtin_amdgcn_global_load_lds((const __attribute__((address_space(1))) void*)g,
                                   (__attribute__((address_space(3))) void*)l, 16, 0, 0);
}

// ---------------- cast kernel (vectorized) + fused c2 norms ----------------
__global__ void cast_all(const float* __restrict__ x, const float* __restrict__ wq,
                         const float* __restrict__ wk, const float* __restrict__ wv,
                         const float* __restrict__ wo, const float* __restrict__ cb,
                         unsigned short* __restrict__ xb, unsigned short* __restrict__ xl,
                         unsigned short* __restrict__ wb, unsigned short* __restrict__ wkl,
                         unsigned short* __restrict__ wob, unsigned short* __restrict__ cbb,
                         unsigned short* __restrict__ cbl, float* __restrict__ c2,
                         float* __restrict__ lsum) {
  if (blockIdx.x >= 4096) {  // c2 blocks (32 x 256 threads)
    int i = (blockIdx.x - 4096) * 256 + threadIdx.x;
    if (i < HH * NC) {
      const float* r = cb + (long)i * HDD;
      double s = 0.0;
      for (int j = 0; j < HDD; j++) s += (double)r[j] * (double)r[j];
      c2[i] = (float)s;
    }
    return;
  }
  long i = (long)blockIdx.x * blockDim.x + threadIdx.x;
  if (i == 0) lsum[0] = 0.f;
  const long NX4 = 1048576, NW4 = 262144, NCB4 = 131072;
  const long TOT4 = NX4 + 4 * NW4 + NCB4;
  for (long q = i; q < TOT4; q += (long)4096 * blockDim.x) {
    if (q < NX4) {
      long t = q * 4;
      float4 v = *(const float4*)(x + t);
      u16x4 hi, lo;
#pragma unroll
      for (int j = 0; j < 4; j++) {
        float f = ((const float*)&v)[j];
        unsigned short h = f2bf(f);
        hi[j] = h; lo[j] = f2bf(f - bf2f(h));
      }
      *(u16x4*)(xb + t) = hi;
      *(u16x4*)(xl + t) = lo;
    } else if (q < NX4 + NW4) {
      long t = (q - NX4) * 4;
      float4 v = *(const float4*)(wq + t);
      u16x4 hi;
#pragma unroll
      for (int j = 0; j < 4; j++) hi[j] = f2bf(((const float*)&v)[j]);
      *(u16x4*)(wb + t) = hi;
    } else if (q < NX4 + 2 * NW4) {
      long t = (q - NX4 - NW4) * 4;
      float4 v = *(const float4*)(wk + t);
      u16x4 hi, lo;
#pragma unroll
      for (int j = 0; j < 4; j++) {
        float f = ((const float*)&v)[j];
        unsigned short h = f2bf(f);
        hi[j] = h; lo[j] = f2bf(f - bf2f(h));
      }
      *(u16x4*)(wb + 1048576 + t) = hi;
      *(u16x4*)(wkl + t) = lo;
    } else if (q < NX4 + 3 * NW4) {
      long t = (q - NX4 - 2 * NW4) * 4;
      float4 v = *(const float4*)(wv + t);
      u16x4 hi;
#pragma unroll
      for (int j = 0; j < 4; j++) hi[j] = f2bf(((const float*)&v)[j]);
      *(u16x4*)(wb + 2097152 + t) = hi;
    } else if (q < NX4 + 4 * NW4) {
      long t = (q - NX4 - 3 * NW4) * 4;
      float4 v = *(const float4*)(wo + t);
      u16x4 hi;
#pragma unroll
      for (int j = 0; j < 4; j++) hi[j] = f2bf(((const float*)&v)[j]);
      *(u16x4*)(wob + t) = hi;
    } else {
      long t = (q - NX4 - 4 * NW4) * 4;
      float4 v = *(const float4*)(cb + t);
      u16x4 hi, lo;
#pragma unroll
      for (int j = 0; j < 4; j++) {
        float f = ((const float*)&v)[j];
        unsigned short h = f2bf(f);
        hi[j] = h; lo[j] = f2bf(f - bf2f(h));
      }
      *(u16x4*)(cbb + t) = hi;
      *(u16x4*)(cbl + t) = lo;
    }
  }
}

// ---------------- HORIZONTAL FUSION: gemm_qv + kvq-64row, BK=32, global_load_lds (R6) ----------------
__global__ __launch_bounds__(256) void qv_kvq(
    const unsigned short* __restrict__ xb, const unsigned short* __restrict__ xl,
    const unsigned short* __restrict__ wb, const unsigned short* __restrict__ wkl,
    const float* __restrict__ cb, const float* __restrict__ c2,
    const unsigned short* __restrict__ cbb, const unsigned short* __restrict__ cbl,
    unsigned short* __restrict__ qb, unsigned short* __restrict__ vt,
    unsigned short* __restrict__ khat, float* __restrict__ scodes,
    float* __restrict__ lsum) {
  __shared__ __align__(16) char smem[37888];
  int tid = threadIdx.x;
  int wave = tid >> 6, lane = tid & 63;
  int quad = lane >> 4, col = lane & 15;
  int gid = blockIdx.x;
  int cls = gid % 3;

  if (cls == 2) {
    // ================= QV path (identical math to gemm_qv) =================
    unsigned short* As = (unsigned short*)smem;           // 8192 B
    unsigned short* Bs = (unsigned short*)(smem + 8192);  // 8192 B
    int qid = gid / 3;                 // 0..511
    int bx = qid & 15, by = qid >> 4;
    int m0 = by * 128;
    int n0 = bx * 128 + (bx >= 8 ? 1024 : 0);
    f32x4 acc[4][4] = {};
    int row_in = (wave << 4) + (lane >> 2);
    int seg = lane & 3;
    const unsigned short* gA0 = xb + (long)(m0 + row_in) * DD + seg * 8;
    const unsigned short* gA1 = xb + (long)(m0 + 64 + row_in) * DD + seg * 8;
    const unsigned short* gB0 = wb + (long)(n0 + row_in) * DD + seg * 8;
    const unsigned short* gB1 = wb + (long)(n0 + 64 + row_in) * DD + seg * 8;
    unsigned short* lA0 = As + wave * 512;
    unsigned short* lA1 = As + 2048 + wave * 512;
    unsigned short* lB0 = Bs + wave * 512;
    unsigned short* lB1 = Bs + 2048 + wave * 512;
    int wm = wave & 1, wn = wave >> 1;
    const unsigned short* pa = As + (wm * 64 + col) * 32 + quad * 8;
    const unsigned short* pb = Bs + (wn * 64 + col) * 32 + quad * 8;
    for (int kk = 0; kk < DD; kk += 32) {
      __syncthreads();
      load_lds16(gA0 + kk, lA0);
      load_lds16(gA1 + kk, lA1);
      load_lds16(gB0 + kk, lB0);
      load_lds16(gB1 + kk, lB1);
      __syncthreads();
      bf16x8 af[4], bfr[4];
      for (int t = 0; t < 4; t++) af[t]  = *(const bf16x8*)(pa + t * 512);
      for (int t = 0; t < 4; t++) bfr[t] = *(const bf16x8*)(pb + t * 512);
      for (int mt = 0; mt < 4; mt++)
        for (int nt = 0; nt < 4; nt++)
          acc[mt][nt] = __builtin_amdgcn_mfma_f32_16x16x32_bf16(af[mt], bfr[nt], acc[mt][nt], 0, 0, 0);
    }
    for (int mt = 0; mt < 4; mt++)
      for (int nt = 0; nt < 4; nt++) {
        int mbase = m0 + wm * 64 + mt * 16 + quad * 4;
        int n = n0 + wn * 64 + nt * 16 + col;
        int which = n >> 10, e = n & 1023;
        int h = e >> 6, hd = e & 63;
        for (int r = 0; r < 4; r++) {
          int m = mbase + r;
          int b = m >> 11, l = m & 2047;
          unsigned short val = f2bf(acc[mt][nt][r]);
          long bh = (long)(b * HH + h);
          if (which == 0)      qb[(bh * LL + l) * HDD + hd] = val;
          else                 vt[(bh * HDD + hd) * LL + l] = val;
        }
      }
    return;
  }

  // ================= KVQ path: 64-row m-tile, fused GEMM+VQ =================
  unsigned short* Ah = (unsigned short*)smem;            // 4096 B
  unsigned short* Al = (unsigned short*)(smem + 4096);   // 4096 B
  unsigned short* Bh = (unsigned short*)(smem + 8192);   // 4096 B
  unsigned short* Bl = (unsigned short*)(smem + 12288);  // 4096 B
  float* kfL = (float*)smem;                             // 17408 B = 64*68*4 (overlays staging)
  unsigned short* CbHb = (unsigned short*)(smem + 17408);// 2 bufs x 4608 B
  unsigned short* CbLb = (unsigned short*)(smem + 26624);// 2 bufs x 4608 B
  float* Cs = (float*)(smem + 35840);                    // 2048 B

  int kid = (gid / 3) * 2 + cls;       // 0..1023
  int mtile = kid & 63;                // 0..63
  int h = kid >> 6;                    // 0..15
  int m0 = mtile * 64;
  int n0 = h * 64;
  int bgl = m0 >> 11;
  int l0 = m0 & 2047;
  long bh = (long)(bgl * HH + h);
  const float* c2h = c2 + h * NC;
  Cs[tid] = c2h[tid];
  Cs[tid + 256] = c2h[tid + 256];

  // ---------- Phase 1: GEMM 64x64 (split-bf16 3-pass) ----------
  f32x4 acc[2][2] = {};
  int row_in = (wave << 4) + (lane >> 2);   // 0..63
  int seg = lane & 3;
  const unsigned short* gAh = xb + (long)(m0 + row_in) * DD + seg * 8;
  const unsigned short* gAl = xl + (long)(m0 + row_in) * DD + seg * 8;
  const unsigned short* gBh = wb + (long)(1048576 + (long)(n0 + row_in) * DD) + seg * 8;
  const unsigned short* gBl = wkl + (long)(n0 + row_in) * DD + seg * 8;
  unsigned short* lAh = Ah + wave * 512;
  unsigned short* lAl = Al + wave * 512;
  unsigned short* lBh = Bh + wave * 512;
  unsigned short* lBl = Bl + wave * 512;
  int wm = wave & 1, wn = wave >> 1;
  const unsigned short* pah = Ah + (wm * 32 + col) * 32 + quad * 8;
  const unsigned short* pal = Al + (wm * 32 + col) * 32 + quad * 8;
  const unsigned short* pbh = Bh + (wn * 32 + col) * 32 + quad * 8;
  const unsigned short* pbl = Bl + (wn * 32 + col) * 32 + quad * 8;
  for (int kk = 0; kk < DD; kk += 32) {
    __syncthreads();
    load_lds16(gAh + kk, lAh);
    load_lds16(gAl + kk, lAl);
    load_lds16(gBh + kk, lBh);
    load_lds16(gBl + kk, lBl);
    __syncthreads();
    bf16x8 ah[2], al[2], bhf[2], blf[2];
    for (int t = 0; t < 2; t++) ah[t] = *(const bf16x8*)(pah + t * 512);
    for (int t = 0; t < 2; t++) al[t] = *(const bf16x8*)(pal + t * 512);
    for (int t = 0; t < 2; t++) bhf[t] = *(const bf16x8*)(pbh + t * 512);
    for (int t = 0; t < 2; t++) blf[t] = *(const bf16x8*)(pbl + t * 512);
    for (int mt = 0; mt < 2; mt++)
      for (int nt = 0; nt < 2; nt++) {
        acc[mt][nt] = __builtin_amdgcn_mfma_f32_16x16x32_bf16(ah[mt], bhf[nt], acc[mt][nt], 0, 0, 0);
        acc[mt][nt] = __builtin_amdgcn_mfma_f32_16x16x32_bf16(ah[mt], blf[nt], acc[mt][nt], 0, 0, 0);
        acc[mt][nt] = __builtin_amdgcn_mfma_f32_16x16x32_bf16(al[mt], bhf[nt], acc[mt][nt], 0, 0, 0);
      }
  }
  // ---------- Phase 2: acc -> kfL[64][68]; stage codebook tile 0 ----------
  __syncthreads();
  const unsigned short* cbbh = cbb + (long)h * NC * HDD;
  const unsigned short* cblh = cbl + (long)h * NC * HDD;
  int srow = tid >> 3;
  int sseg = (tid & 7) * 8;
  const unsigned short* gH = cbbh + (long)srow * HDD + sseg;
  const unsigned short* gL = cblh + (long)srow * HDD + sseg;
  int ldsOff = srow * 72 + sseg;
  u16x8 ph0 = *(const u16x8*)(gH);
  u16x8 pl0 = *(const u16x8*)(gL);
  for (int mt = 0; mt < 2; mt++)
    for (int nt = 0; nt < 2; nt++) {
      int rw = wm * 32 + mt * 16 + quad * 4;
      int hd = wn * 32 + nt * 16 + col;
      for (int r = 0; r < 4; r++)
        kfL[(rw + r) * 68 + hd] = acc[mt][nt][r];
    }
  *(u16x8*)(CbHb + ldsOff) = ph0;
  *(u16x8*)(CbLb + ldsOff) = pl0;
  __syncthreads();

  // ---------- Phase 3: VQ rounds (16 rows/wave) ----------
  bf16x8 bh0, bh1, bl0, bl1;
  float k2;
  {
    const float* kp = kfL + (wave * 16 + col) * 68 + quad * 8;
    float4 t0 = *(const float4*)(kp);
    float4 t1 = *(const float4*)(kp + 4);
    float4 t2 = *(const float4*)(kp + 32);
    float4 t3 = *(const float4*)(kp + 36);
    float fv[16];
    fv[0]=t0.x; fv[1]=t0.y; fv[2]=t0.z; fv[3]=t0.w;
    fv[4]=t1.x; fv[5]=t1.y; fv[6]=t1.z; fv[7]=t1.w;
    fv[8]=t2.x; fv[9]=t2.y; fv[10]=t2.z; fv[11]=t2.w;
    fv[12]=t3.x; fv[13]=t3.y; fv[14]=t3.z; fv[15]=t3.w;
    k2 = 0.f;
#pragma unroll
    for (int j = 0; j < 16; j++) k2 = fmaf(fv[j], fv[j], k2);
    k2 += __shfl_xor(k2, 16);
    k2 += __shfl_xor(k2, 32);
    u16x8 h0, h1, l0u, l1u;
#pragma unroll
    for (int j = 0; j < 8; j++) {
      unsigned short hi = f2bf(fv[j]);
      h0[j] = hi; l0u[j] = f2bf(fv[j] - bf2f(hi));
      unsigned short hi2 = f2bf(fv[8 + j]);
      h1[j] = hi2; l1u[j] = f2bf(fv[8 + j] - bf2f(hi2));
    }
    bh0 = __builtin_bit_cast(bf16x8, h0);
    bh1 = __builtin_bit_cast(bf16x8, h1);
    bl0 = __builtin_bit_cast(bf16x8, l0u);
    bl1 = __builtin_bit_cast(bf16x8, l1u);
  }
  float b1v = 1e38f, b2v = 1e38f;
  int b1i = 0x7fffffff, b2i = 0x7fffffff;
  for (int t = 0; t < 16; t++) {
    int cur = t & 1;
    u16x8 nh, nl;
    if (t < 15) {
      nh = *(const u16x8*)(gH + (t + 1) * 32 * HDD);
      nl = *(const u16x8*)(gL + (t + 1) * 32 * HDD);
    }
    const unsigned short* CbHc = CbHb + cur * 2304;
    const unsigned short* CbLc = CbLb + cur * 2304;
#pragma unroll
    for (int s = 0; s < 2; s++) {
      const unsigned short* rp = CbHc + (s * 16 + col) * 72 + quad * 8;
      const unsigned short* rq = CbLc + (s * 16 + col) * 72 + quad * 8;
      bf16x8 ah0 = *(const bf16x8*)(rp);
      bf16x8 ah1 = *(const bf16x8*)(rp + 32);
      bf16x8 al0 = *(const bf16x8*)(rq);
      bf16x8 al1 = *(const bf16x8*)(rq + 32);
      f32x4 aP = {}, aQ = {};
      aP = __builtin_amdgcn_mfma_f32_16x16x32_bf16(ah0, bh0, aP, 0, 0, 0);
      aQ = __builtin_amdgcn_mfma_f32_16x16x32_bf16(ah1, bh1, aQ, 0, 0, 0);
      aP = __builtin_amdgcn_mfma_f32_16x16x32_bf16(al0, bh0, aP, 0, 0, 0);
      aQ = __builtin_amdgcn_mfma_f32_16x16x32_bf16(al1, bh1, aQ, 0, 0, 0);
      aP = __builtin_amdgcn_mfma_f32_16x16x32_bf16(ah0, bl0, aP, 0, 0, 0);
      aQ = __builtin_amdgcn_mfma_f32_16x16x32_bf16(ah1, bl1, aQ, 0, 0, 0);
      f32x4 c2v = *(const f32x4*)(Cs + t * 32 + s * 16 + quad * 4);
#pragma unroll
      for (int r = 0; r < 4; r++) {
        float val = c2v[r] - 2.0f * (aP[r] + aQ[r]);
        int idx = t * 32 + s * 16 + quad * 4 + r;
        if (val < b1v) { b2v = b1v; b2i = b1i; b1v = val; b1i = idx; }
        else if (val < b2v) { b2v = val; b2i = idx; }
      }
    }
    if (t < 15) {
      *(u16x8*)(CbHb + (cur ^ 1) * 2304 + ldsOff) = nh;
      *(u16x8*)(CbLb + (cur ^ 1) * 2304 + ldsOff) = nl;
    }
    __syncthreads();
  }
#pragma unroll
  for (int d = 16; d <= 32; d <<= 1) {
    float o1v = __shfl_xor(b1v, d); int o1i = __shfl_xor(b1i, d);
    float o2v = __shfl_xor(b2v, d); int o2i = __shfl_xor(b2i, d);
    if (o1v < b1v || (o1v == b1v && o1i < b1i)) {
      float nv; int ni;
      if (b1v < o2v || (b1v == o2v && b1i < o2i)) { nv = b1v; ni = b1i; }
      else { nv = o2v; ni = o2i; }
      b1v = o1v; b1i = o1i; b2v = nv; b2i = ni;
    } else {
      if (o1v < b2v || (o1v == b2v && o1i < b2i)) { b2v = o1v; b2i = o1i; }
    }
  }
  const float DMARG = 0.015625f;
  bool trig = (b2v - b1v <= DMARG);
  float part;
  int widx = b1i;
  if (__any(trig)) {
    const float* kpr = kfL + (wave * 16 + col) * 68 + quad * 8;
    float4 f0 = *(const float4*)(kpr);
    float4 f1 = *(const float4*)(kpr + 4);
    float4 f2 = *(const float4*)(kpr + 32);
    float4 f3 = *(const float4*)(kpr + 36);
    const float* c1p = cb + ((long)h * NC + b1i) * HDD + quad * 8;
    const float* c2p = cb + ((long)h * NC + b2i) * HDD + quad * 8;
    float4 a0 = *(const float4*)(c1p);
    float4 a1 = *(const float4*)(c1p + 4);
    float4 a2 = *(const float4*)(c1p + 32);
    float4 a3 = *(const float4*)(c1p + 36);
    float4 e0 = *(const float4*)(c2p);
    float4 e1 = *(const float4*)(c2p + 4);
    float4 e2 = *(const float4*)(c2p + 32);
    float4 e3 = *(const float4*)(c2p + 36);
    float s1 = 0.f, s2 = 0.f;
#pragma unroll
    for (int j = 0; j < 4; j++) {
      float d;
      d = ((const float*)&f0)[j] - ((const float*)&a0)[j]; s1 = fmaf(d, d, s1);
      d = ((const float*)&f1)[j] - ((const float*)&a1)[j]; s1 = fmaf(d, d, s1);
      d = ((const float*)&f2)[j] - ((const float*)&a2)[j]; s1 = fmaf(d, d, s1);
      d = ((const float*)&f3)[j] - ((const float*)&a3)[j]; s1 = fmaf(d, d, s1);
      d = ((const float*)&f0)[j] - ((const float*)&e0)[j]; s2 = fmaf(d, d, s2);
      d = ((const float*)&f1)[j] - ((const float*)&e1)[j]; s2 = fmaf(d, d, s2);
      d = ((const float*)&f2)[j] - ((const float*)&e2)[j]; s2 = fmaf(d, d, s2);
      d = ((const float*)&f3)[j] - ((const float*)&e3)[j]; s2 = fmaf(d, d, s2);
    }
    s1 += __shfl_xor(s1, 16); s1 += __shfl_xor(s1, 32);
    s2 += __shfl_xor(s2, 16); s2 += __shfl_xor(s2, 32);
    if (trig) {
      if (s2 < s1 || (s2 == s1 && b2i < b1i)) { widx = b2i; part = s2; }
      else { widx = b1i; part = s1; }
    } else {
      part = k2 + b1v;
    }
  } else {
    part = k2 + b1v;
  }
  if (quad != 0) part = 0.f;
  part += __shfl_xor(part, 1);  part += __shfl_xor(part, 2);
  part += __shfl_xor(part, 4);  part += __shfl_xor(part, 8);
  part += __shfl_xor(part, 16); part += __shfl_xor(part, 32);
  if (lane == 0) atomicAdd(lsum, part);
  if (lane < 16)
    scodes[bh * LL + l0 + wave * 16 + lane] = (float)widx;
  // per-wave khat scatter via shfl (16 rows x 64 shorts)
  {
    int rL = lane >> 2;                 // 0..15
    int p = (lane & 3) * 16;
    int code = __shfl(widx, rL);        // lanes 0..15 hold widx for row=lane
    const unsigned short* src = cbbh + (long)code * HDD + p;
    unsigned short* dst = khat + (bh * LL + l0 + wave * 16 + rL) * HDD + p;
    *(u16x8*)(dst)     = *(const u16x8*)(src);
    *(u16x8*)(dst + 8) = *(const u16x8*)(src + 8);
  }
}

// ---------------- flash attention: paired q-tiles, swapped QK^T, K/V DOUBLE-BUFFER (1 barrier/iter) ----------------
// Per iter kt: {write regs(kt)->buf[cur]; barrier; issue loads(kt+1)->regs; compute buf[cur]}.
// buf[cur] writes at kt are separated from its last reads (kt-2 compute) by the kt-1 barrier.
// T5 setprio around MFMA clusters (independent blocks per CU at different phases).
__global__ __launch_bounds__(256) void attn_kernel(
    const unsigned short* __restrict__ qb, const unsigned short* __restrict__ khat,
    const unsigned short* __restrict__ vt, unsigned short* __restrict__ attnb) {
  __shared__ __align__(16) unsigned short Pbuf[4][2][16 * 72];  // 18432 B
  __shared__ __align__(16) unsigned short Kbuf[2][64 * 72];     // 18432 B
  __shared__ __align__(16) unsigned short Vbuf[2][64 * 72];     // 18432 B
  int tid = threadIdx.x, wave = tid >> 6, lane = tid & 63;
  int quad = lane >> 4, col = lane & 15;
  int id = blockIdx.y * 16 + blockIdx.x;
  int xcd = id & 7, sidx = id >> 3;
  int bh = xcd * 4 + (sidx >> 4);
  int pi = sidx & 15;
  int b = bh >> 4, h = bh & 15;
  int ta = pi, tb = 31 - pi;
  int qbA = ta * 64 + wave * 16;
  int qbB = tb * 64 + wave * 16;
  const unsigned short* qrA = qb + ((long)bh * LL + qbA + col) * HDD;
  const unsigned short* qrB = qb + ((long)bh * LL + qbB + col) * HDD;
  bf16x8 aqA0 = *(const bf16x8*)(qrA + quad * 8);
  bf16x8 aqA1 = *(const bf16x8*)(qrA + 32 + quad * 8);
  bf16x8 aqB0 = *(const bf16x8*)(qrB + quad * 8);
  bf16x8 aqB1 = *(const bf16x8*)(qrB + 32 + quad * 8);
  float lA = 0.f, lB = 0.f;
  f32x4 oA[4] = {}, oB[4] = {};
  unsigned short* PA = Pbuf[wave][0];
  unsigned short* PB = Pbuf[wave][1];
  const unsigned short* kh = khat + (long)bh * LL * HDD;
  const unsigned short* vh = vt + (long)bh * HDD * LL;
  int srow = tid >> 2, sc = (tid & 3) * 8;
  const unsigned short* gK = kh + (long)srow * HDD + sc;
  const unsigned short* gV = vh + (long)srow * LL + sc;
  int wOff = srow * 72 + sc;
  const float SCL = 0.18033688011112042f;  // log2(e) / 8
  u16x8 rk0 = *(const u16x8*)(gK);
  u16x8 rk1 = *(const u16x8*)(gK + 32);
  u16x8 rv0 = *(const u16x8*)(gV);
  u16x8 rv1 = *(const u16x8*)(gV + 32);
  for (int kt = 0; kt <= tb; kt++) {
    int cur = kt & 1;
    int kbase = kt * 64;
    bool actA = (kt <= ta);
    // write this tile's regs into buf[cur]
    {
      unsigned short* lK = Kbuf[cur] + wOff;
      unsigned short* lV = Vbuf[cur] + wOff;
      *(u16x8*)lK        = rk0;
      *(u16x8*)(lK + 32) = rk1;
      *(u16x8*)lV        = rv0;
      *(u16x8*)(lV + 32) = rv1;
    }
    __syncthreads();
    if (kt < tb) {  // issue next-tile loads; consumed at next iter's write
      const unsigned short* nK = gK + (long)(kt + 1) * 64 * HDD;
      const unsigned short* nV = gV + (kt + 1) * 64;
      rk0 = *(const u16x8*)(nK);
      rk1 = *(const u16x8*)(nK + 32);
      rv0 = *(const u16x8*)(nV);
      rv1 = *(const u16x8*)(nV + 32);
    }
    f32x4 zA[4], zB[4];
    __builtin_amdgcn_s_setprio(1);
    for (int nt = 0; nt < 4; nt++) {
      const unsigned short* krow = Kbuf[cur] + (nt * 16 + col) * 72;
      bf16x8 k0 = *(const bf16x8*)(krow + quad * 8);
      bf16x8 k1 = *(const bf16x8*)(krow + 32 + quad * 8);
      f32x4 z = {};
      z = __builtin_amdgcn_mfma_f32_16x16x32_bf16(k0, aqB0, z, 0, 0, 0);
      z = __builtin_amdgcn_mfma_f32_16x16x32_bf16(k1, aqB1, z, 0, 0, 0);
      zB[nt] = z;
      if (actA) {
        f32x4 y = {};
        y = __builtin_amdgcn_mfma_f32_16x16x32_bf16(k0, aqA0, y, 0, 0, 0);
        y = __builtin_amdgcn_mfma_f32_16x16x32_bf16(k1, aqA1, y, 0, 0, 0);
        zA[nt] = y;
      }
    }
    __builtin_amdgcn_s_setprio(0);
    for (int nt = 0; nt < 4; nt++) {
      u16x4 pk;
      for (int r = 0; r < 4; r++) {
        float sc2 = zB[nt][r] * SCL;
        int key = kbase + nt * 16 + quad * 4 + r;
        if (kt == tb && key > qbB + col) sc2 = -1e30f;
        float p = exp2f(sc2);
        lB += p;
        pk[r] = __builtin_bit_cast(unsigned short, (__bf16)p);
      }
      *(u16x4*)(PB + col * 72 + nt * 16 + quad * 4) = pk;
    }
    if (actA) {
      for (int nt = 0; nt < 4; nt++) {
        u16x4 pk;
        for (int r = 0; r < 4; r++) {
          float sc2 = zA[nt][r] * SCL;
          int key = kbase + nt * 16 + quad * 4 + r;
          if (kt == ta && key > qbA + col) sc2 = -1e30f;
          float p = exp2f(sc2);
          lA += p;
          pk[r] = __builtin_bit_cast(unsigned short, (__bf16)p);
        }
        *(u16x4*)(PA + col * 72 + nt * 16 + quad * 4) = pk;
      }
    }
    bf16x8 apB0 = *(const bf16x8*)(PB + col * 72 + quad * 8);
    bf16x8 apB1 = *(const bf16x8*)(PB + col * 72 + 32 + quad * 8);
    bf16x8 apA0, apA1;
    if (actA) {
      apA0 = *(const bf16x8*)(PA + col * 72 + quad * 8);
      apA1 = *(const bf16x8*)(PA + col * 72 + 32 + quad * 8);
    }
    __builtin_amdgcn_s_setprio(1);
    for (int nt = 0; nt < 4; nt++) {
      const unsigned short* vrow = Vbuf[cur] + (nt * 16 + col) * 72;
      bf16x8 v0 = *(const bf16x8*)(vrow + quad * 8);
      bf16x8 v1 = *(const bf16x8*)(vrow + 32 + quad * 8);
      oB[nt] = __builtin_amdgcn_mfma_f32_16x16x32_bf16(apB0, v0, oB[nt], 0, 0, 0);
      oB[nt] = __builtin_amdgcn_mfma_f32_16x16x32_bf16(apB1, v1, oB[nt], 0, 0, 0);
      if (actA) {
        oA[nt] = __builtin_amdgcn_mfma_f32_16x16x32_bf16(apA0, v0, oA[nt], 0, 0, 0);
        oA[nt] = __builtin_amdgcn_mfma_f32_16x16x32_bf16(apA1, v1, oA[nt], 0, 0, 0);
      }
    }
    __builtin_amdgcn_s_setprio(0);
  }
  lA += __shfl_xor(lA, 16); lA += __shfl_xor(lA, 32);
  lB += __shfl_xor(lB, 16); lB += __shfl_xor(lB, 32);
  float invAc = 1.0f / lA;
  float invBc = 1.0f / lB;
  for (int r = 0; r < 4; r++) {
    float invA = __shfl(invAc, quad * 4 + r);
    float invB = __shfl(invBc, quad * 4 + r);
    int rowA = qbA + quad * 4 + r;
    int rowB = qbB + quad * 4 + r;
    for (int nt = 0; nt < 4; nt++) {
      int hd = nt * 16 + col;
      attnb[((long)b * LL + rowA) * DD + h * HDD + hd] = f2bf(oA[nt][r] * invA);
      attnb[((long)b * LL + rowB) * DD + h * HDD + hd] = f2bf(oB[nt][r] * invB);
    }
  }
}

// ---------------- GEMM2: out = attn * Wo^T, 128x64 tiles, BK=32, global_load_lds (R6) ----------------
__global__ __launch_bounds__(256) void gemm_out(
    const unsigned short* __restrict__ attnb, const unsigned short* __restrict__ wob,
    float* __restrict__ out) {
  __shared__ __align__(16) unsigned short As[128 * 32];
  __shared__ __align__(16) unsigned short Bs[64 * 32];
  int tid = threadIdx.x;
  int wave = tid >> 6, lane = tid & 63;
  int quad = lane >> 4, col = lane & 15;
  int m0 = blockIdx.y * 128;
  int n0 = blockIdx.x * 64;
  f32x4 acc[4][2] = {};
  int row_in = (wave << 4) + (lane >> 2);
  int seg = lane & 3;
  const unsigned short* gA0 = attnb + (long)(m0 + row_in) * DD + seg * 8;
  const unsigned short* gA1 = attnb + (long)(m0 + 64 + row_in) * DD + seg * 8;
  const unsigned short* gB0 = wob + (long)(n0 + row_in) * DD + seg * 8;
  unsigned short* lA0 = As + wave * 512;
  unsigned short* lA1 = As + 2048 + wave * 512;
  unsigned short* lB0 = Bs + wave * 512;
  int wm = wave & 1, wn = wave >> 1;
  const unsigned short* pa = As + (wm * 64 + col) * 32 + quad * 8;
  const unsigned short* pb = Bs + (wn * 32 + col) * 32 + quad * 8;
  for (int kk = 0; kk < DD; kk += 32) {
    __syncthreads();
    load_lds16(gA0 + kk, lA0);
    load_lds16(gA1 + kk, lA1);
    load_lds16(gB0 + kk, lB0);
    __syncthreads();
    bf16x8 af[4], bfr[2];
    for (int t = 0; t < 4; t++) af[t]  = *(const bf16x8*)(pa + t * 512);
    for (int t = 0; t < 2; t++) bfr[t] = *(const bf16x8*)(pb + t * 512);
    for (int mt = 0; mt < 4; mt++)
      for (int nt = 0; nt < 2; nt++)
        acc[mt][nt] = __builtin_amdgcn_mfma_f32_16x16x32_bf16(af[mt], bfr[nt], acc[mt][nt], 0, 0, 0);
  }
  for (int mt = 0; mt < 4; mt++)
    for (int nt = 0; nt < 2; nt++) {
      int mbase = m0 + wm * 64 + mt * 16 + quad * 4;
      int n = n0 + wn * 32 + nt * 16 + col;
      for (int r = 0; r < 4; r++)
        out[(long)(mbase + r) * DD + n] = acc[mt][nt][r];
    }
}

// ---------------- finalize scalars ----------------
__global__ void finalize(const float* __restrict__ lsum, float* __restrict__ out) {
  if (threadIdx.x == 0) {
    float v = lsum[0] / (float)(BB * HH * LL);
    out[4194304] = v;
    out[4194305] = v;
  }
}

extern "C" void kernel_launch(void* const* d_in, const int* in_sizes, int n_in,
                              void* d_out, int out_size, void* d_ws, size_t ws_size,
                              hipStream_t stream) {
  const float* x  = (const float*)d_in[0];
  const float* wq = (const float*)d_in[1];
  const float* wk = (const float*)d_in[2];
  const float* wv = (const float*)d_in[3];
  const float* wo = (const float*)d_in[4];
  const float* cb = (const float*)d_in[5];
  float* out = (float*)d_out;

  char* ws = (char*)d_ws;
  size_t off = 0;
  auto alloc = [&](size_t bytes) {
    void* p = ws + off;
    off = (off + bytes + 255) & ~(size_t)255;
    return p;
  };
  unsigned short* xb    = (unsigned short*)alloc(4194304 * 2);
  unsigned short* xl    = (unsigned short*)alloc(4194304 * 2);
  unsigned short* wb    = (unsigned short*)alloc(3145728 * 2);
  unsigned short* wkl   = (unsigned short*)alloc(1048576 * 2);
  unsigned short* wob   = (unsigned short*)alloc(1048576 * 2);
  unsigned short* cbb   = (unsigned short*)alloc(524288 * 2);
  unsigned short* cbl   = (unsigned short*)alloc(524288 * 2);
  unsigned short* qb    = (unsigned short*)alloc(4194304 * 2);
  unsigned short* vt    = (unsigned short*)alloc(4194304 * 2);
  unsigned short* khat  = (unsigned short*)alloc(4194304 * 2);
  unsigned short* attnb = (unsigned short*)alloc(4194304 * 2);
  float* c2   = (float*)alloc(8192 * 4);
  float* lsum = (float*)alloc(256);

  cast_all<<<dim3(4128), dim3(256), 0, stream>>>(x, wq, wk, wv, wo, cb, xb, xl, wb, wkl, wob, cbb, cbl, c2, lsum);
  qv_kvq<<<dim3(1536), dim3(256), 0, stream>>>(xb, xl, wb, wkl, cb, c2, cbb, cbl, qb, vt, khat, out + 4194306, lsum);
  attn_kernel<<<dim3(16, 32), dim3(256), 0, stream>>>(qb, khat, vt, attnb);
  gemm_out<<<dim3(16, 32), dim3(256), 0, stream>>>(attnb, wob, out);
  finalize<<<dim3(1), dim3(64), 0, stream>>>(lsum, out);
}

// Round 11
// 272.149 us; speedup vs baseline: 1.0431x; 1.0093x over previous
//
#include <hip/hip_runtime.h>
#include <stdint.h>

#define BB 2
#define HH 16
#define LL 2048
#define DD 1024
#define HDD 64
#define NC 512

typedef __bf16 bf16x8 __attribute__((ext_vector_type(8)));
typedef float f32x4 __attribute__((ext_vector_type(4)));
typedef unsigned short u16x8 __attribute__((ext_vector_type(8)));
typedef unsigned short u16x4 __attribute__((ext_vector_type(4)));

__device__ __forceinline__ unsigned short f2bf(float f) {
  union { float f; unsigned u; } v; v.f = f;
  unsigned u = v.u;
  u += 0x7fffu + ((u >> 16) & 1u);
  return (unsigned short)(u >> 16);
}
__device__ __forceinline__ float bf2f(unsigned short h) {
  union { unsigned u; float f; } v; v.u = ((unsigned)h) << 16;
  return v.f;
}

// async global->LDS, 16B per lane; lds ptr must be wave-uniform base (HW adds lane*16)
__device__ __forceinline__ void load_lds16(const unsigned short* g, unsigned short* l) {
  __builtin_amdgcn_global_load_lds((const __attribute__((address_space(1))) void*)g,
                                   (__attribute__((address_space(3))) void*)l, 16, 0, 0);
}

// ---------------- cast kernel (vectorized) + fused c2 norms ----------------
__global__ void cast_all(const float* __restrict__ x, const float* __restrict__ wq,
                         const float* __restrict__ wk, const float* __restrict__ wv,
                         const float* __restrict__ wo, const float* __restrict__ cb,
                         unsigned short* __restrict__ xb, unsigned short* __restrict__ xl,
                         unsigned short* __restrict__ wb, unsigned short* __restrict__ wkl,
                         unsigned short* __restrict__ wob, unsigned short* __restrict__ cbb,
                         unsigned short* __restrict__ cbl, float* __restrict__ c2,
                         float* __restrict__ lsum) {
  if (blockIdx.x >= 4096) {  // c2 blocks (32 x 256 threads)
    int i = (blockIdx.x - 4096) * 256 + threadIdx.x;
    if (i < HH * NC) {
      const float* r = cb + (long)i * HDD;
      double s = 0.0;
      for (int j = 0; j < HDD; j++) s += (double)r[j] * (double)r[j];
      c2[i] = (float)s;
    }
    return;
  }
  long i = (long)blockIdx.x * blockDim.x + threadIdx.x;
  if (i == 0) lsum[0] = 0.f;
  const long NX4 = 1048576, NW4 = 262144, NCB4 = 131072;
  const long TOT4 = NX4 + 4 * NW4 + NCB4;
  for (long q = i; q < TOT4; q += (long)4096 * blockDim.x) {
    if (q < NX4) {
      long t = q * 4;
      float4 v = *(const float4*)(x + t);
      u16x4 hi, lo;
#pragma unroll
      for (int j = 0; j < 4; j++) {
        float f = ((const float*)&v)[j];
        unsigned short h = f2bf(f);
        hi[j] = h; lo[j] = f2bf(f - bf2f(h));
      }
      *(u16x4*)(xb + t) = hi;
      *(u16x4*)(xl + t) = lo;
    } else if (q < NX4 + NW4) {
      long t = (q - NX4) * 4;
      float4 v = *(const float4*)(wq + t);
      u16x4 hi;
#pragma unroll
      for (int j = 0; j < 4; j++) hi[j] = f2bf(((const float*)&v)[j]);
      *(u16x4*)(wb + t) = hi;
    } else if (q < NX4 + 2 * NW4) {
      long t = (q - NX4 - NW4) * 4;
      float4 v = *(const float4*)(wk + t);
      u16x4 hi, lo;
#pragma unroll
      for (int j = 0; j < 4; j++) {
        float f = ((const float*)&v)[j];
        unsigned short h = f2bf(f);
        hi[j] = h; lo[j] = f2bf(f - bf2f(h));
      }
      *(u16x4*)(wb + 1048576 + t) = hi;
      *(u16x4*)(wkl + t) = lo;
    } else if (q < NX4 + 3 * NW4) {
      long t = (q - NX4 - 2 * NW4) * 4;
      float4 v = *(const float4*)(wv + t);
      u16x4 hi;
#pragma unroll
      for (int j = 0; j < 4; j++) hi[j] = f2bf(((const float*)&v)[j]);
      *(u16x4*)(wb + 2097152 + t) = hi;
    } else if (q < NX4 + 4 * NW4) {
      long t = (q - NX4 - 3 * NW4) * 4;
      float4 v = *(const float4*)(wo + t);
      u16x4 hi;
#pragma unroll
      for (int j = 0; j < 4; j++) hi[j] = f2bf(((const float*)&v)[j]);
      *(u16x4*)(wob + t) = hi;
    } else {
      long t = (q - NX4 - 4 * NW4) * 4;
      float4 v = *(const float4*)(cb + t);
      u16x4 hi, lo;
#pragma unroll
      for (int j = 0; j < 4; j++) {
        float f = ((const float*)&v)[j];
        unsigned short h = f2bf(f);
        hi[j] = h; lo[j] = f2bf(f - bf2f(h));
      }
      *(u16x4*)(cbb + t) = hi;
      *(u16x4*)(cbl + t) = lo;
    }
  }
}

// ---------------- HORIZONTAL FUSION: gemm_qv + kvq-64row, BK=32, global_load_lds (R6) ----------------
__global__ __launch_bounds__(256) void qv_kvq(
    const unsigned short* __restrict__ xb, const unsigned short* __restrict__ xl,
    const unsigned short* __restrict__ wb, const unsigned short* __restrict__ wkl,
    const float* __restrict__ cb, const float* __restrict__ c2,
    const unsigned short* __restrict__ cbb, const unsigned short* __restrict__ cbl,
    unsigned short* __restrict__ qb, unsigned short* __restrict__ vt,
    unsigned short* __restrict__ khat, float* __restrict__ scodes,
    float* __restrict__ lsum) {
  __shared__ __align__(16) char smem[37888];
  int tid = threadIdx.x;
  int wave = tid >> 6, lane = tid & 63;
  int quad = lane >> 4, col = lane & 15;
  int gid = blockIdx.x;
  int cls = gid % 3;

  if (cls == 2) {
    // ================= QV path (identical math to gemm_qv) =================
    unsigned short* As = (unsigned short*)smem;           // 8192 B
    unsigned short* Bs = (unsigned short*)(smem + 8192);  // 8192 B
    int qid = gid / 3;                 // 0..511
    int bx = qid & 15, by = qid >> 4;
    int m0 = by * 128;
    int n0 = bx * 128 + (bx >= 8 ? 1024 : 0);
    f32x4 acc[4][4] = {};
    int row_in = (wave << 4) + (lane >> 2);
    int seg = lane & 3;
    const unsigned short* gA0 = xb + (long)(m0 + row_in) * DD + seg * 8;
    const unsigned short* gA1 = xb + (long)(m0 + 64 + row_in) * DD + seg * 8;
    const unsigned short* gB0 = wb + (long)(n0 + row_in) * DD + seg * 8;
    const unsigned short* gB1 = wb + (long)(n0 + 64 + row_in) * DD + seg * 8;
    unsigned short* lA0 = As + wave * 512;
    unsigned short* lA1 = As + 2048 + wave * 512;
    unsigned short* lB0 = Bs + wave * 512;
    unsigned short* lB1 = Bs + 2048 + wave * 512;
    int wm = wave & 1, wn = wave >> 1;
    const unsigned short* pa = As + (wm * 64 + col) * 32 + quad * 8;
    const unsigned short* pb = Bs + (wn * 64 + col) * 32 + quad * 8;
    for (int kk = 0; kk < DD; kk += 32) {
      __syncthreads();
      load_lds16(gA0 + kk, lA0);
      load_lds16(gA1 + kk, lA1);
      load_lds16(gB0 + kk, lB0);
      load_lds16(gB1 + kk, lB1);
      __syncthreads();
      bf16x8 af[4], bfr[4];
      for (int t = 0; t < 4; t++) af[t]  = *(const bf16x8*)(pa + t * 512);
      for (int t = 0; t < 4; t++) bfr[t] = *(const bf16x8*)(pb + t * 512);
      for (int mt = 0; mt < 4; mt++)
        for (int nt = 0; nt < 4; nt++)
          acc[mt][nt] = __builtin_amdgcn_mfma_f32_16x16x32_bf16(af[mt], bfr[nt], acc[mt][nt], 0, 0, 0);
    }
    for (int mt = 0; mt < 4; mt++)
      for (int nt = 0; nt < 4; nt++) {
        int mbase = m0 + wm * 64 + mt * 16 + quad * 4;
        int n = n0 + wn * 64 + nt * 16 + col;
        int which = n >> 10, e = n & 1023;
        int h = e >> 6, hd = e & 63;
        for (int r = 0; r < 4; r++) {
          int m = mbase + r;
          int b = m >> 11, l = m & 2047;
          unsigned short val = f2bf(acc[mt][nt][r]);
          long bh = (long)(b * HH + h);
          if (which == 0)      qb[(bh * LL + l) * HDD + hd] = val;
          else                 vt[(bh * HDD + hd) * LL + l] = val;
        }
      }
    return;
  }

  // ================= KVQ path: 64-row m-tile, fused GEMM+VQ =================
  unsigned short* Ah = (unsigned short*)smem;            // 4096 B
  unsigned short* Al = (unsigned short*)(smem + 4096);   // 4096 B
  unsigned short* Bh = (unsigned short*)(smem + 8192);   // 4096 B
  unsigned short* Bl = (unsigned short*)(smem + 12288);  // 4096 B
  float* kfL = (float*)smem;                             // 17408 B = 64*68*4 (overlays staging)
  unsigned short* CbHb = (unsigned short*)(smem + 17408);// 2 bufs x 4608 B
  unsigned short* CbLb = (unsigned short*)(smem + 26624);// 2 bufs x 4608 B
  float* Cs = (float*)(smem + 35840);                    // 2048 B

  int kid = (gid / 3) * 2 + cls;       // 0..1023
  int mtile = kid & 63;                // 0..63
  int h = kid >> 6;                    // 0..15
  int m0 = mtile * 64;
  int n0 = h * 64;
  int bgl = m0 >> 11;
  int l0 = m0 & 2047;
  long bh = (long)(bgl * HH + h);
  const float* c2h = c2 + h * NC;
  Cs[tid] = c2h[tid];
  Cs[tid + 256] = c2h[tid + 256];

  // ---------- Phase 1: GEMM 64x64 (split-bf16 3-pass) ----------
  f32x4 acc[2][2] = {};
  int row_in = (wave << 4) + (lane >> 2);   // 0..63
  int seg = lane & 3;
  const unsigned short* gAh = xb + (long)(m0 + row_in) * DD + seg * 8;
  const unsigned short* gAl = xl + (long)(m0 + row_in) * DD + seg * 8;
  const unsigned short* gBh = wb + (long)(1048576 + (long)(n0 + row_in) * DD) + seg * 8;
  const unsigned short* gBl = wkl + (long)(n0 + row_in) * DD + seg * 8;
  unsigned short* lAh = Ah + wave * 512;
  unsigned short* lAl = Al + wave * 512;
  unsigned short* lBh = Bh + wave * 512;
  unsigned short* lBl = Bl + wave * 512;
  int wm = wave & 1, wn = wave >> 1;
  const unsigned short* pah = Ah + (wm * 32 + col) * 32 + quad * 8;
  const unsigned short* pal = Al + (wm * 32 + col) * 32 + quad * 8;
  const unsigned short* pbh = Bh + (wn * 32 + col) * 32 + quad * 8;
  const unsigned short* pbl = Bl + (wn * 32 + col) * 32 + quad * 8;
  for (int kk = 0; kk < DD; kk += 32) {
    __syncthreads();
    load_lds16(gAh + kk, lAh);
    load_lds16(gAl + kk, lAl);
    load_lds16(gBh + kk, lBh);
    load_lds16(gBl + kk, lBl);
    __syncthreads();
    bf16x8 ah[2], al[2], bhf[2], blf[2];
    for (int t = 0; t < 2; t++) ah[t] = *(const bf16x8*)(pah + t * 512);
    for (int t = 0; t < 2; t++) al[t] = *(const bf16x8*)(pal + t * 512);
    for (int t = 0; t < 2; t++) bhf[t] = *(const bf16x8*)(pbh + t * 512);
    for (int t = 0; t < 2; t++) blf[t] = *(const bf16x8*)(pbl + t * 512);
    for (int mt = 0; mt < 2; mt++)
      for (int nt = 0; nt < 2; nt++) {
        acc[mt][nt] = __builtin_amdgcn_mfma_f32_16x16x32_bf16(ah[mt], bhf[nt], acc[mt][nt], 0, 0, 0);
        acc[mt][nt] = __builtin_amdgcn_mfma_f32_16x16x32_bf16(ah[mt], blf[nt], acc[mt][nt], 0, 0, 0);
        acc[mt][nt] = __builtin_amdgcn_mfma_f32_16x16x32_bf16(al[mt], bhf[nt], acc[mt][nt], 0, 0, 0);
      }
  }
  // ---------- Phase 2: acc -> kfL[64][68]; stage codebook tile 0 ----------
  __syncthreads();
  const unsigned short* cbbh = cbb + (long)h * NC * HDD;
  const unsigned short* cblh = cbl + (long)h * NC * HDD;
  int srow = tid >> 3;
  int sseg = (tid & 7) * 8;
  const unsigned short* gH = cbbh + (long)srow * HDD + sseg;
  const unsigned short* gL = cblh + (long)srow * HDD + sseg;
  int ldsOff = srow * 72 + sseg;
  u16x8 ph0 = *(const u16x8*)(gH);
  u16x8 pl0 = *(const u16x8*)(gL);
  for (int mt = 0; mt < 2; mt++)
    for (int nt = 0; nt < 2; nt++) {
      int rw = wm * 32 + mt * 16 + quad * 4;
      int hd = wn * 32 + nt * 16 + col;
      for (int r = 0; r < 4; r++)
        kfL[(rw + r) * 68 + hd] = acc[mt][nt][r];
    }
  *(u16x8*)(CbHb + ldsOff) = ph0;
  *(u16x8*)(CbLb + ldsOff) = pl0;
  __syncthreads();

  // ---------- Phase 3: VQ rounds (16 rows/wave) ----------
  bf16x8 bh0, bh1, bl0, bl1;
  float k2;
  {
    const float* kp = kfL + (wave * 16 + col) * 68 + quad * 8;
    float4 t0 = *(const float4*)(kp);
    float4 t1 = *(const float4*)(kp + 4);
    float4 t2 = *(const float4*)(kp + 32);
    float4 t3 = *(const float4*)(kp + 36);
    float fv[16];
    fv[0]=t0.x; fv[1]=t0.y; fv[2]=t0.z; fv[3]=t0.w;
    fv[4]=t1.x; fv[5]=t1.y; fv[6]=t1.z; fv[7]=t1.w;
    fv[8]=t2.x; fv[9]=t2.y; fv[10]=t2.z; fv[11]=t2.w;
    fv[12]=t3.x; fv[13]=t3.y; fv[14]=t3.z; fv[15]=t3.w;
    k2 = 0.f;
#pragma unroll
    for (int j = 0; j < 16; j++) k2 = fmaf(fv[j], fv[j], k2);
    k2 += __shfl_xor(k2, 16);
    k2 += __shfl_xor(k2, 32);
    u16x8 h0, h1, l0u, l1u;
#pragma unroll
    for (int j = 0; j < 8; j++) {
      unsigned short hi = f2bf(fv[j]);
      h0[j] = hi; l0u[j] = f2bf(fv[j] - bf2f(hi));
      unsigned short hi2 = f2bf(fv[8 + j]);
      h1[j] = hi2; l1u[j] = f2bf(fv[8 + j] - bf2f(hi2));
    }
    bh0 = __builtin_bit_cast(bf16x8, h0);
    bh1 = __builtin_bit_cast(bf16x8, h1);
    bl0 = __builtin_bit_cast(bf16x8, l0u);
    bl1 = __builtin_bit_cast(bf16x8, l1u);
  }
  float b1v = 1e38f, b2v = 1e38f;
  int b1i = 0x7fffffff, b2i = 0x7fffffff;
  for (int t = 0; t < 16; t++) {
    int cur = t & 1;
    u16x8 nh, nl;
    if (t < 15) {
      nh = *(const u16x8*)(gH + (t + 1) * 32 * HDD);
      nl = *(const u16x8*)(gL + (t + 1) * 32 * HDD);
    }
    const unsigned short* CbHc = CbHb + cur * 2304;
    const unsigned short* CbLc = CbLb + cur * 2304;
#pragma unroll
    for (int s = 0; s < 2; s++) {
      const unsigned short* rp = CbHc + (s * 16 + col) * 72 + quad * 8;
      const unsigned short* rq = CbLc + (s * 16 + col) * 72 + quad * 8;
      bf16x8 ah0 = *(const bf16x8*)(rp);
      bf16x8 ah1 = *(const bf16x8*)(rp + 32);
      bf16x8 al0 = *(const bf16x8*)(rq);
      bf16x8 al1 = *(const bf16x8*)(rq + 32);
      f32x4 aP = {}, aQ = {};
      aP = __builtin_amdgcn_mfma_f32_16x16x32_bf16(ah0, bh0, aP, 0, 0, 0);
      aQ = __builtin_amdgcn_mfma_f32_16x16x32_bf16(ah1, bh1, aQ, 0, 0, 0);
      aP = __builtin_amdgcn_mfma_f32_16x16x32_bf16(al0, bh0, aP, 0, 0, 0);
      aQ = __builtin_amdgcn_mfma_f32_16x16x32_bf16(al1, bh1, aQ, 0, 0, 0);
      aP = __builtin_amdgcn_mfma_f32_16x16x32_bf16(ah0, bl0, aP, 0, 0, 0);
      aQ = __builtin_amdgcn_mfma_f32_16x16x32_bf16(ah1, bl1, aQ, 0, 0, 0);
      f32x4 c2v = *(const f32x4*)(Cs + t * 32 + s * 16 + quad * 4);
#pragma unroll
      for (int r = 0; r < 4; r++) {
        float val = c2v[r] - 2.0f * (aP[r] + aQ[r]);
        int idx = t * 32 + s * 16 + quad * 4 + r;
        if (val < b1v) { b2v = b1v; b2i = b1i; b1v = val; b1i = idx; }
        else if (val < b2v) { b2v = val; b2i = idx; }
      }
    }
    if (t < 15) {
      *(u16x8*)(CbHb + (cur ^ 1) * 2304 + ldsOff) = nh;
      *(u16x8*)(CbLb + (cur ^ 1) * 2304 + ldsOff) = nl;
    }
    __syncthreads();
  }
#pragma unroll
  for (int d = 16; d <= 32; d <<= 1) {
    float o1v = __shfl_xor(b1v, d); int o1i = __shfl_xor(b1i, d);
    float o2v = __shfl_xor(b2v, d); int o2i = __shfl_xor(b2i, d);
    if (o1v < b1v || (o1v == b1v && o1i < b1i)) {
      float nv; int ni;
      if (b1v < o2v || (b1v == o2v && b1i < o2i)) { nv = b1v; ni = b1i; }
      else { nv = o2v; ni = o2i; }
      b1v = o1v; b1i = o1i; b2v = nv; b2i = ni;
    } else {
      if (o1v < b2v || (o1v == b2v && o1i < b2i)) { b2v = o1v; b2i = o1i; }
    }
  }
  const float DMARG = 0.015625f;
  bool trig = (b2v - b1v <= DMARG);
  float part;
  int widx = b1i;
  if (__any(trig)) {
    const float* kpr = kfL + (wave * 16 + col) * 68 + quad * 8;
    float4 f0 = *(const float4*)(kpr);
    float4 f1 = *(const float4*)(kpr + 4);
    float4 f2 = *(const float4*)(kpr + 32);
    float4 f3 = *(const float4*)(kpr + 36);
    const float* c1p = cb + ((long)h * NC + b1i) * HDD + quad * 8;
    const float* c2p = cb + ((long)h * NC + b2i) * HDD + quad * 8;
    float4 a0 = *(const float4*)(c1p);
    float4 a1 = *(const float4*)(c1p + 4);
    float4 a2 = *(const float4*)(c1p + 32);
    float4 a3 = *(const float4*)(c1p + 36);
    float4 e0 = *(const float4*)(c2p);
    float4 e1 = *(const float4*)(c2p + 4);
    float4 e2 = *(const float4*)(c2p + 32);
    float4 e3 = *(const float4*)(c2p + 36);
    float s1 = 0.f, s2 = 0.f;
#pragma unroll
    for (int j = 0; j < 4; j++) {
      float d;
      d = ((const float*)&f0)[j] - ((const float*)&a0)[j]; s1 = fmaf(d, d, s1);
      d = ((const float*)&f1)[j] - ((const float*)&a1)[j]; s1 = fmaf(d, d, s1);
      d = ((const float*)&f2)[j] - ((const float*)&a2)[j]; s1 = fmaf(d, d, s1);
      d = ((const float*)&f3)[j] - ((const float*)&a3)[j]; s1 = fmaf(d, d, s1);
      d = ((const float*)&f0)[j] - ((const float*)&e0)[j]; s2 = fmaf(d, d, s2);
      d = ((const float*)&f1)[j] - ((const float*)&e1)[j]; s2 = fmaf(d, d, s2);
      d = ((const float*)&f2)[j] - ((const float*)&e2)[j]; s2 = fmaf(d, d, s2);
      d = ((const float*)&f3)[j] - ((const float*)&e3)[j]; s2 = fmaf(d, d, s2);
    }
    s1 += __shfl_xor(s1, 16); s1 += __shfl_xor(s1, 32);
    s2 += __shfl_xor(s2, 16); s2 += __shfl_xor(s2, 32);
    if (trig) {
      if (s2 < s1 || (s2 == s1 && b2i < b1i)) { widx = b2i; part = s2; }
      else { widx = b1i; part = s1; }
    } else {
      part = k2 + b1v;
    }
  } else {
    part = k2 + b1v;
  }
  if (quad != 0) part = 0.f;
  part += __shfl_xor(part, 1);  part += __shfl_xor(part, 2);
  part += __shfl_xor(part, 4);  part += __shfl_xor(part, 8);
  part += __shfl_xor(part, 16); part += __shfl_xor(part, 32);
  if (lane == 0) atomicAdd(lsum, part);
  if (lane < 16)
    scodes[bh * LL + l0 + wave * 16 + lane] = (float)widx;
  // per-wave khat scatter via shfl (16 rows x 64 shorts)
  {
    int rL = lane >> 2;                 // 0..15
    int p = (lane & 3) * 16;
    int code = __shfl(widx, rL);        // lanes 0..15 hold widx for row=lane
    const unsigned short* src = cbbh + (long)code * HDD + p;
    unsigned short* dst = khat + (bh * LL + l0 + wave * 16 + rL) * HDD + p;
    *(u16x8*)(dst)     = *(const u16x8*)(src);
    *(u16x8*)(dst + 8) = *(const u16x8*)(src + 8);
  }
}

// ---------------- flash attention: paired q-tiles, swapped QK^T, SHARED per-wave P buffer ----------------
// P is wave-local (no barrier between P write and read) so PA/PB share ONE 16x72
// buffer: full B sequence, then A reuses it. LDS = 27648 B -> 5 blocks/CU (was 2).
// K/V single-buffer, 2 barriers/iter, reg-prefetch (R6-R8 proven structure).
__global__ __launch_bounds__(256) void attn_kernel(
    const unsigned short* __restrict__ qb, const unsigned short* __restrict__ khat,
    const unsigned short* __restrict__ vt, unsigned short* __restrict__ attnb) {
  __shared__ __align__(16) unsigned short Pbuf[4][16 * 72];  // 9216 B (shared A/B)
  __shared__ __align__(16) unsigned short Kbuf[64 * 72];     // 9216 B
  __shared__ __align__(16) unsigned short Vbuf[64 * 72];     // 9216 B
  int tid = threadIdx.x, wave = tid >> 6, lane = tid & 63;
  int quad = lane >> 4, col = lane & 15;
  int id = blockIdx.y * 16 + blockIdx.x;
  int xcd = id & 7, sidx = id >> 3;
  int bh = xcd * 4 + (sidx >> 4);
  int pi = sidx & 15;
  int b = bh >> 4, h = bh & 15;
  int ta = pi, tb = 31 - pi;
  int qbA = ta * 64 + wave * 16;
  int qbB = tb * 64 + wave * 16;
  const unsigned short* qrA = qb + ((long)bh * LL + qbA + col) * HDD;
  const unsigned short* qrB = qb + ((long)bh * LL + qbB + col) * HDD;
  bf16x8 aqA0 = *(const bf16x8*)(qrA + quad * 8);
  bf16x8 aqA1 = *(const bf16x8*)(qrA + 32 + quad * 8);
  bf16x8 aqB0 = *(const bf16x8*)(qrB + quad * 8);
  bf16x8 aqB1 = *(const bf16x8*)(qrB + 32 + quad * 8);
  float lA = 0.f, lB = 0.f;
  f32x4 oA[4] = {}, oB[4] = {};
  unsigned short* P = Pbuf[wave];
  const unsigned short* kh = khat + (long)bh * LL * HDD;
  const unsigned short* vh = vt + (long)bh * HDD * LL;
  int srow = tid >> 2, sc = (tid & 3) * 8;
  const unsigned short* gK = kh + (long)srow * HDD + sc;
  const unsigned short* gV = vh + (long)srow * LL + sc;
  unsigned short* lK = Kbuf + srow * 72 + sc;
  unsigned short* lV = Vbuf + srow * 72 + sc;
  const float SCL = 0.18033688011112042f;  // log2(e) / 8
  u16x8 rk0 = *(const u16x8*)(gK);
  u16x8 rk1 = *(const u16x8*)(gK + 32);
  u16x8 rv0 = *(const u16x8*)(gV);
  u16x8 rv1 = *(const u16x8*)(gV + 32);
  for (int kt = 0; kt <= tb; kt++) {
    int kbase = kt * 64;
    bool actA = (kt <= ta);
    __syncthreads();
    *(u16x8*)lK        = rk0;
    *(u16x8*)(lK + 32) = rk1;
    *(u16x8*)lV        = rv0;
    *(u16x8*)(lV + 32) = rv1;
    __syncthreads();
    if (kt < tb) {  // issue next-tile loads; latency hides under this tile's compute
      const unsigned short* nK = gK + (long)(kt + 1) * 64 * HDD;
      const unsigned short* nV = gV + (kt + 1) * 64;
      rk0 = *(const u16x8*)(nK);
      rk1 = *(const u16x8*)(nK + 32);
      rv0 = *(const u16x8*)(nV);
      rv1 = *(const u16x8*)(nV + 32);
    }
    f32x4 zA[4], zB[4];
    __builtin_amdgcn_s_setprio(1);
    for (int nt = 0; nt < 4; nt++) {
      const unsigned short* krow = Kbuf + (nt * 16 + col) * 72;
      bf16x8 k0 = *(const bf16x8*)(krow + quad * 8);
      bf16x8 k1 = *(const bf16x8*)(krow + 32 + quad * 8);
      f32x4 z = {};
      z = __builtin_amdgcn_mfma_f32_16x16x32_bf16(k0, aqB0, z, 0, 0, 0);
      z = __builtin_amdgcn_mfma_f32_16x16x32_bf16(k1, aqB1, z, 0, 0, 0);
      zB[nt] = z;
      if (actA) {
        f32x4 y = {};
        y = __builtin_amdgcn_mfma_f32_16x16x32_bf16(k0, aqA0, y, 0, 0, 0);
        y = __builtin_amdgcn_mfma_f32_16x16x32_bf16(k1, aqA1, y, 0, 0, 0);
        zA[nt] = y;
      }
    }
    __builtin_amdgcn_s_setprio(0);
    // ---- B sequence: softmax -> P -> PV (wave-local P, no barrier needed) ----
    for (int nt = 0; nt < 4; nt++) {
      u16x4 pk;
      for (int r = 0; r < 4; r++) {
        float sc2 = zB[nt][r] * SCL;
        int key = kbase + nt * 16 + quad * 4 + r;
        if (kt == tb && key > qbB + col) sc2 = -1e30f;
        float p = exp2f(sc2);
        lB += p;
        pk[r] = __builtin_bit_cast(unsigned short, (__bf16)p);
      }
      *(u16x4*)(P + col * 72 + nt * 16 + quad * 4) = pk;
    }
    {
      bf16x8 ap0 = *(const bf16x8*)(P + col * 72 + quad * 8);
      bf16x8 ap1 = *(const bf16x8*)(P + col * 72 + 32 + quad * 8);
      __builtin_amdgcn_s_setprio(1);
      for (int nt = 0; nt < 4; nt++) {
        const unsigned short* vrow = Vbuf + (nt * 16 + col) * 72;
        bf16x8 v0 = *(const bf16x8*)(vrow + quad * 8);
        bf16x8 v1 = *(const bf16x8*)(vrow + 32 + quad * 8);
        oB[nt] = __builtin_amdgcn_mfma_f32_16x16x32_bf16(ap0, v0, oB[nt], 0, 0, 0);
        oB[nt] = __builtin_amdgcn_mfma_f32_16x16x32_bf16(ap1, v1, oB[nt], 0, 0, 0);
      }
      __builtin_amdgcn_s_setprio(0);
    }
    // ---- A sequence: reuse the same P buffer ----
    if (actA) {
      for (int nt = 0; nt < 4; nt++) {
        u16x4 pk;
        for (int r = 0; r < 4; r++) {
          float sc2 = zA[nt][r] * SCL;
          int key = kbase + nt * 16 + quad * 4 + r;
          if (kt == ta && key > qbA + col) sc2 = -1e30f;
          float p = exp2f(sc2);
          lA += p;
          pk[r] = __builtin_bit_cast(unsigned short, (__bf16)p);
        }
        *(u16x4*)(P + col * 72 + nt * 16 + quad * 4) = pk;
      }
      bf16x8 ap0 = *(const bf16x8*)(P + col * 72 + quad * 8);
      bf16x8 ap1 = *(const bf16x8*)(P + col * 72 + 32 + quad * 8);
      __builtin_amdgcn_s_setprio(1);
      for (int nt = 0; nt < 4; nt++) {
        const unsigned short* vrow = Vbuf + (nt * 16 + col) * 72;
        bf16x8 v0 = *(const bf16x8*)(vrow + quad * 8);
        bf16x8 v1 = *(const bf16x8*)(vrow + 32 + quad * 8);
        oA[nt] = __builtin_amdgcn_mfma_f32_16x16x32_bf16(ap0, v0, oA[nt], 0, 0, 0);
        oA[nt] = __builtin_amdgcn_mfma_f32_16x16x32_bf16(ap1, v1, oA[nt], 0, 0, 0);
      }
      __builtin_amdgcn_s_setprio(0);
    }
  }
  lA += __shfl_xor(lA, 16); lA += __shfl_xor(lA, 32);
  lB += __shfl_xor(lB, 16); lB += __shfl_xor(lB, 32);
  float invAc = 1.0f / lA;
  float invBc = 1.0f / lB;
  for (int r = 0; r < 4; r++) {
    float invA = __shfl(invAc, quad * 4 + r);
    float invB = __shfl(invBc, quad * 4 + r);
    int rowA = qbA + quad * 4 + r;
    int rowB = qbB + quad * 4 + r;
    for (int nt = 0; nt < 4; nt++) {
      int hd = nt * 16 + col;
      attnb[((long)b * LL + rowA) * DD + h * HDD + hd] = f2bf(oA[nt][r] * invA);
      attnb[((long)b * LL + rowB) * DD + h * HDD + hd] = f2bf(oB[nt][r] * invB);
    }
  }
}

// ---------------- GEMM2: out = attn * Wo^T, 128x64, BK=32 + fused finalize ----------------
__global__ __launch_bounds__(256) void gemm_out(
    const unsigned short* __restrict__ attnb, const unsigned short* __restrict__ wob,
    const float* __restrict__ lsum, float* __restrict__ out) {
  __shared__ __align__(16) unsigned short As[128 * 32];
  __shared__ __align__(16) unsigned short Bs[64 * 32];
  int tid = threadIdx.x;
  int wave = tid >> 6, lane = tid & 63;
  int quad = lane >> 4, col = lane & 15;
  int m0 = blockIdx.y * 128;
  int n0 = blockIdx.x * 64;
  f32x4 acc[4][2] = {};
  int row_in = (wave << 4) + (lane >> 2);
  int seg = lane & 3;
  const unsigned short* gA0 = attnb + (long)(m0 + row_in) * DD + seg * 8;
  const unsigned short* gA1 = attnb + (long)(m0 + 64 + row_in) * DD + seg * 8;
  const unsigned short* gB0 = wob + (long)(n0 + row_in) * DD + seg * 8;
  unsigned short* lA0 = As + wave * 512;
  unsigned short* lA1 = As + 2048 + wave * 512;
  unsigned short* lB0 = Bs + wave * 512;
  int wm = wave & 1, wn = wave >> 1;
  const unsigned short* pa = As + (wm * 64 + col) * 32 + quad * 8;
  const unsigned short* pb = Bs + (wn * 32 + col) * 32 + quad * 8;
  for (int kk = 0; kk < DD; kk += 32) {
    __syncthreads();
    load_lds16(gA0 + kk, lA0);
    load_lds16(gA1 + kk, lA1);
    load_lds16(gB0 + kk, lB0);
    __syncthreads();
    bf16x8 af[4], bfr[2];
    for (int t = 0; t < 4; t++) af[t]  = *(const bf16x8*)(pa + t * 512);
    for (int t = 0; t < 2; t++) bfr[t] = *(const bf16x8*)(pb + t * 512);
    for (int mt = 0; mt < 4; mt++)
      for (int nt = 0; nt < 2; nt++)
        acc[mt][nt] = __builtin_amdgcn_mfma_f32_16x16x32_bf16(af[mt], bfr[nt], acc[mt][nt], 0, 0, 0);
  }
  for (int mt = 0; mt < 4; mt++)
    for (int nt = 0; nt < 2; nt++) {
      int mbase = m0 + wm * 64 + mt * 16 + quad * 4;
      int n = n0 + wn * 32 + nt * 16 + col;
      for (int r = 0; r < 4; r++)
        out[(long)(mbase + r) * DD + n] = acc[mt][nt][r];
    }
  if (blockIdx.x == 0 && blockIdx.y == 0 && tid == 0) {
    float v = lsum[0] / (float)(BB * HH * LL);
    out[4194304] = v;
    out[4194305] = v;
  }
}

extern "C" void kernel_launch(void* const* d_in, const int* in_sizes, int n_in,
                              void* d_out, int out_size, void* d_ws, size_t ws_size,
                              hipStream_t stream) {
  const float* x  = (const float*)d_in[0];
  const float* wq = (const float*)d_in[1];
  const float* wk = (const float*)d_in[2];
  const float* wv = (const float*)d_in[3];
  const float* wo = (const float*)d_in[4];
  const float* cb = (const float*)d_in[5];
  float* out = (float*)d_out;

  char* ws = (char*)d_ws;
  size_t off = 0;
  auto alloc = [&](size_t bytes) {
    void* p = ws + off;
    off = (off + bytes + 255) & ~(size_t)255;
    return p;
  };
  unsigned short* xb    = (unsigned short*)alloc(4194304 * 2);
  unsigned short* xl    = (unsigned short*)alloc(4194304 * 2);
  unsigned short* wb    = (unsigned short*)alloc(3145728 * 2);
  unsigned short* wkl   = (unsigned short*)alloc(1048576 * 2);
  unsigned short* wob   = (unsigned short*)alloc(1048576 * 2);
  unsigned short* cbb   = (unsigned short*)alloc(524288 * 2);
  unsigned short* cbl   = (unsigned short*)alloc(524288 * 2);
  unsigned short* qb    = (unsigned short*)alloc(4194304 * 2);
  unsigned short* vt    = (unsigned short*)alloc(4194304 * 2);
  unsigned short* khat  = (unsigned short*)alloc(4194304 * 2);
  unsigned short* attnb = (unsigned short*)alloc(4194304 * 2);
  float* c2   = (float*)alloc(8192 * 4);
  float* lsum = (float*)alloc(256);

  cast_all<<<dim3(4128), dim3(256), 0, stream>>>(x, wq, wk, wv, wo, cb, xb, xl, wb, wkl, wob, cbb, cbl, c2, lsum);
  qv_kvq<<<dim3(1536), dim3(256), 0, stream>>>(xb, xl, wb, wkl, cb, c2, cbb, cbl, qb, vt, khat, out + 4194306, lsum);
  attn_kernel<<<dim3(16, 32), dim3(256), 0, stream>>>(qb, khat, vt, attnb);
  gemm_out<<<dim3(16, 32), dim3(256), 0, stream>>>(attnb, wob, lsum, out);
}